// Round 1
// baseline (2007.266 us; speedup 1.0000x reference)
//
#include <hip/hip_runtime.h>
#include <hip/hip_bf16.h>

#define DIM 2048
#define S_LEN 2048
#define N_HEADS 32
#define N_KV_HEADS 8
#define HEAD_DIM 64
#define KV_DIM (N_KV_HEADS * HEAD_DIM)   // 512

// ---------------------------------------------------------------------------
// Tiled fp32 GEMM: C[M,N] = A[M,K] @ B[K,N].  64x64 tile, 256 threads,
// 4x4 outputs/thread, K-tile 16. M,N,K multiples of 64/16 (true here).
// ---------------------------------------------------------------------------
__global__ __launch_bounds__(256) void gemm_tile(const float* __restrict__ A,
                                                 const float* __restrict__ B,
                                                 float* __restrict__ C,
                                                 int M, int N, int K) {
    __shared__ float As[16][68];  // As[k][m], pad 68 -> 272B rows (16B aligned)
    __shared__ float Bs[16][68];  // Bs[k][n]
    const int tid = threadIdx.x;
    const int bx = blockIdx.x, by = blockIdx.y;
    const int tx = tid & 15;      // n-group
    const int ty = tid >> 4;      // m-group
    float acc[4][4];
#pragma unroll
    for (int i = 0; i < 4; i++)
#pragma unroll
        for (int j = 0; j < 4; j++) acc[i][j] = 0.f;

    for (int k0 = 0; k0 < K; k0 += 16) {
#pragma unroll
        for (int i = 0; i < 4; i++) {
            int idx = tid + i * 256;          // 0..1023
            int m  = idx >> 4;                // 0..63
            int kk = idx & 15;                // 0..15
            As[kk][m] = A[(size_t)(by * 64 + m) * K + k0 + kk];
            int k2 = idx >> 6;                // 0..15
            int n  = idx & 63;                // 0..63
            Bs[k2][n] = B[(size_t)(k0 + k2) * N + bx * 64 + n];
        }
        __syncthreads();
#pragma unroll
        for (int kk = 0; kk < 16; kk++) {
            float4 a4 = *(const float4*)&As[kk][ty * 4];
            float4 b4 = *(const float4*)&Bs[kk][tx * 4];
            float a[4] = {a4.x, a4.y, a4.z, a4.w};
            float b[4] = {b4.x, b4.y, b4.z, b4.w};
#pragma unroll
            for (int i = 0; i < 4; i++)
#pragma unroll
                for (int j = 0; j < 4; j++) acc[i][j] += a[i] * b[j];
        }
        __syncthreads();
    }
#pragma unroll
    for (int i = 0; i < 4; i++) {
        float4 o = make_float4(acc[i][0], acc[i][1], acc[i][2], acc[i][3]);
        *(float4*)&C[(size_t)(by * 64 + ty * 4 + i) * N + bx * 64 + tx * 4] = o;
    }
}

// ---------------------------------------------------------------------------
// RoPE applied in-place to q (S x 2048) and k (S x 512).
// Pair i of head h lives at cols h*64 + 2i, h*64 + 2i + 1.
// ---------------------------------------------------------------------------
__global__ __launch_bounds__(256) void rope_kernel(float* __restrict__ q,
                                                   float* __restrict__ k,
                                                   const float* __restrict__ fcos,
                                                   const float* __restrict__ fsin) {
    const int idx = blockIdx.x * 256 + threadIdx.x;
    const int nq = S_LEN * N_HEADS * 32;      // q pairs
    float* t;
    int s, i;
    if (idx < nq) {
        s = idx >> 10;                        // / (32 heads * 32 pairs)
        int rem = idx & 1023;
        int h = rem >> 5;
        i = rem & 31;
        t = q + (size_t)s * DIM + h * 64 + 2 * i;
    } else {
        int j = idx - nq;
        s = j >> 8;                           // / (8 heads * 32 pairs)
        int rem = j & 255;
        int h = rem >> 5;
        i = rem & 31;
        t = k + (size_t)s * KV_DIM + h * 64 + 2 * i;
    }
    float c = fcos[s * 32 + i];
    float sn = fsin[s * 32 + i];
    float a = t[0], b = t[1];
    t[0] = a * c - b * sn;
    t[1] = a * sn + b * c;
}

// ---------------------------------------------------------------------------
// Flash-style causal attention, fp32.  One block = (head h, 32-row Q tile).
// Online softmax over 32-row K/V tiles.  Thread t: output row t/8,
// cols (t&7)*8 .. +8; score row t/8, cols (t&7)*4 .. +4.
// ---------------------------------------------------------------------------
__global__ __launch_bounds__(256) void attn_kernel(const float* __restrict__ q,
                                                   const float* __restrict__ k,
                                                   const float* __restrict__ v,
                                                   float* __restrict__ out) {
    const int h = blockIdx.y;                 // 0..31
    const int q0 = blockIdx.x * 32;
    const int kh = h >> 2;                    // kv head
    const int t = threadIdx.x;

    __shared__ float Qs[32][68];
    __shared__ float Ks[32][68];
    __shared__ float Vs[32][68];
    __shared__ float Sx[32][36];
    __shared__ float mrow[32], lrow[32], arow[32];

#pragma unroll
    for (int i = 0; i < 8; i++) {
        int idx = t + i * 256;
        int r = idx >> 6, d = idx & 63;
        Qs[r][d] = q[(size_t)(q0 + r) * DIM + h * 64 + d];
    }
    if (t < 32) { mrow[t] = -3e38f; lrow[t] = 0.f; }

    float acc[8];
#pragma unroll
    for (int c = 0; c < 8; c++) acc[c] = 0.f;

    const int r_o = t >> 3;                   // row 0..31
    const int c0 = (t & 7) * 8;               // output col base
    const int sj0 = (t & 7) * 4;              // score col base
    __syncthreads();

    for (int k0 = 0; k0 <= q0; k0 += 32) {
#pragma unroll
        for (int i = 0; i < 8; i++) {
            int idx = t + i * 256;
            int r = idx >> 6, d = idx & 63;
            Ks[r][d] = k[(size_t)(k0 + r) * KV_DIM + kh * 64 + d];
            Vs[r][d] = v[(size_t)(k0 + r) * KV_DIM + kh * 64 + d];
        }
        __syncthreads();

        // scores: 4 per thread
#pragma unroll
        for (int jj = 0; jj < 4; jj++) {
            int j = sj0 + jj;
            float dotv = 0.f;
            const float* qr = &Qs[r_o][0];
            const float* kr = &Ks[j][0];
#pragma unroll
            for (int d = 0; d < 64; d += 4) {
                float4 q4 = *(const float4*)(qr + d);
                float4 k4 = *(const float4*)(kr + d);
                dotv += q4.x * k4.x + q4.y * k4.y + q4.z * k4.z + q4.w * k4.w;
            }
            dotv *= 0.125f;                   // 1/sqrt(64)
            if (k0 + j > q0 + r_o) dotv = -3e38f;   // causal mask
            Sx[r_o][j] = dotv;
        }
        __syncthreads();

        // online softmax row update (one thread per row)
        if (t < 32) {
            float m_old = mrow[t];
            float mx = m_old;
#pragma unroll
            for (int j = 0; j < 32; j++) mx = fmaxf(mx, Sx[t][j]);
            float al = __expf(m_old - mx);
            float sum = 0.f;
#pragma unroll
            for (int j = 0; j < 32; j++) {
                float p = __expf(Sx[t][j] - mx);
                Sx[t][j] = p;
                sum += p;
            }
            lrow[t] = lrow[t] * al + sum;
            mrow[t] = mx;
            arow[t] = al;
        }
        __syncthreads();

        // O = O*alpha + P @ V
        float al = arow[r_o];
#pragma unroll
        for (int c = 0; c < 8; c++) acc[c] *= al;
#pragma unroll
        for (int j = 0; j < 32; j++) {
            float p = Sx[r_o][j];
#pragma unroll
            for (int c = 0; c < 8; c++) acc[c] += p * Vs[j][c0 + c];
        }
        __syncthreads();
    }

    float inv_l = 1.f / lrow[r_o];
#pragma unroll
    for (int c = 0; c < 8; c++)
        out[(size_t)(q0 + r_o) * DIM + h * 64 + c0 + c] = acc[c] * inv_l;
}

// ---------------------------------------------------------------------------
extern "C" void kernel_launch(void* const* d_in, const int* in_sizes, int n_in,
                              void* d_out, int out_size, void* d_ws, size_t ws_size,
                              hipStream_t stream) {
    const float* x    = (const float*)d_in[0];
    const float* wq   = (const float*)d_in[1];
    const float* wk   = (const float*)d_in[2];
    const float* wv   = (const float*)d_in[3];
    const float* wo   = (const float*)d_in[4];
    const float* fcos = (const float*)d_in[5];
    const float* fsin = (const float*)d_in[6];
    // d_in[7] = mask (we implement causal directly), d_in[8] = start_pos (==0)

    float* qb   = (float*)d_ws;                       // 2048 x 2048
    float* kb   = qb + (size_t)S_LEN * DIM;           // 2048 x 512
    float* vb   = kb + (size_t)S_LEN * KV_DIM;        // 2048 x 512
    float* attn = vb + (size_t)S_LEN * KV_DIM;        // 2048 x 2048

    // QKV projections
    gemm_tile<<<dim3(DIM / 64, S_LEN / 64), 256, 0, stream>>>(x, wq, qb, S_LEN, DIM, DIM);
    gemm_tile<<<dim3(KV_DIM / 64, S_LEN / 64), 256, 0, stream>>>(x, wk, kb, S_LEN, KV_DIM, DIM);
    gemm_tile<<<dim3(KV_DIM / 64, S_LEN / 64), 256, 0, stream>>>(x, wv, vb, S_LEN, KV_DIM, DIM);

    // RoPE on q and k
    int total_pairs = S_LEN * N_HEADS * 32 + S_LEN * N_KV_HEADS * 32;  // 2,621,440
    rope_kernel<<<total_pairs / 256, 256, 0, stream>>>(qb, kb, fcos, fsin);

    // causal attention
    attn_kernel<<<dim3(S_LEN / 32, N_HEADS), 256, 0, stream>>>(qb, kb, vb, attn);

    // output projection
    gemm_tile<<<dim3(DIM / 64, S_LEN / 64), 256, 0, stream>>>(attn, wo, (float*)d_out, S_LEN, DIM, DIM);
}

// Round 2
// 1069.375 us; speedup vs baseline: 1.8770x; 1.8770x over previous
//
#include <hip/hip_runtime.h>
#include <hip/hip_bf16.h>

#define DIM 2048
#define S_LEN 2048
#define N_HEADS 32
#define N_KV_HEADS 8
#define HEAD_DIM 64
#define KV_DIM (N_KV_HEADS * HEAD_DIM)   // 512

typedef __attribute__((ext_vector_type(8))) short bf16x8;
typedef __attribute__((ext_vector_type(4))) float f32x4;

__device__ __forceinline__ unsigned short bf16_of(float f) {
    __hip_bfloat16 h = __float2bfloat16(f);
    return *reinterpret_cast<unsigned short*>(&h);
}

// ---------------------------------------------------------------------------
// Tiled fp32 GEMM: C[M,N] = A[M,K] @ B[K,N].  64x64 tile, 256 threads,
// 4x4 outputs/thread, K-tile 16.
// ---------------------------------------------------------------------------
__global__ __launch_bounds__(256) void gemm_tile(const float* __restrict__ A,
                                                 const float* __restrict__ B,
                                                 float* __restrict__ C,
                                                 int M, int N, int K) {
    __shared__ float As[16][68];
    __shared__ float Bs[16][68];
    const int tid = threadIdx.x;
    const int bx = blockIdx.x, by = blockIdx.y;
    const int tx = tid & 15;
    const int ty = tid >> 4;
    float acc[4][4];
#pragma unroll
    for (int i = 0; i < 4; i++)
#pragma unroll
        for (int j = 0; j < 4; j++) acc[i][j] = 0.f;

    for (int k0 = 0; k0 < K; k0 += 16) {
#pragma unroll
        for (int i = 0; i < 4; i++) {
            int idx = tid + i * 256;
            int m  = idx >> 4;
            int kk = idx & 15;
            As[kk][m] = A[(size_t)(by * 64 + m) * K + k0 + kk];
            int k2 = idx >> 6;
            int n  = idx & 63;
            Bs[k2][n] = B[(size_t)(k0 + k2) * N + bx * 64 + n];
        }
        __syncthreads();
#pragma unroll
        for (int kk = 0; kk < 16; kk++) {
            float4 a4 = *(const float4*)&As[kk][ty * 4];
            float4 b4 = *(const float4*)&Bs[kk][tx * 4];
            float a[4] = {a4.x, a4.y, a4.z, a4.w};
            float b[4] = {b4.x, b4.y, b4.z, b4.w};
#pragma unroll
            for (int i = 0; i < 4; i++)
#pragma unroll
                for (int j = 0; j < 4; j++) acc[i][j] += a[i] * b[j];
        }
        __syncthreads();
    }
#pragma unroll
    for (int i = 0; i < 4; i++) {
        float4 o = make_float4(acc[i][0], acc[i][1], acc[i][2], acc[i][3]);
        *(float4*)&C[(size_t)(by * 64 + ty * 4 + i) * N + bx * 64 + tx * 4] = o;
    }
}

// ---------------------------------------------------------------------------
// RoPE in-place on q (S x 2048) and k (S x 512), fp32.
// ---------------------------------------------------------------------------
__global__ __launch_bounds__(256) void rope_kernel(float* __restrict__ q,
                                                   float* __restrict__ k,
                                                   const float* __restrict__ fcos,
                                                   const float* __restrict__ fsin) {
    const int idx = blockIdx.x * 256 + threadIdx.x;
    const int nq = S_LEN * N_HEADS * 32;
    float* t;
    int s, i;
    if (idx < nq) {
        s = idx >> 10;
        int rem = idx & 1023;
        int h = rem >> 5;
        i = rem & 31;
        t = q + (size_t)s * DIM + h * 64 + 2 * i;
    } else {
        int j = idx - nq;
        s = j >> 8;
        int rem = j & 255;
        int h = rem >> 5;
        i = rem & 31;
        t = k + (size_t)s * KV_DIM + h * 64 + 2 * i;
    }
    float c = fcos[s * 32 + i];
    float sn = fsin[s * 32 + i];
    float a = t[0], b = t[1];
    t[0] = a * c - b * sn;
    t[1] = a * sn + b * c;
}

// ---------------------------------------------------------------------------
// Convert rope'd q and k (fp32) to bf16, straight layout.
// ---------------------------------------------------------------------------
__global__ __launch_bounds__(256) void convert_qk(const float* __restrict__ qb,
                                                  const float* __restrict__ kb,
                                                  unsigned short* __restrict__ qbf,
                                                  unsigned short* __restrict__ kbf) {
    int idx = blockIdx.x * 256 + threadIdx.x;   // float4 index
    const int nq4 = S_LEN * DIM / 4;
    const float* src;
    unsigned short* dst;
    int i;
    if (idx < nq4) { src = qb; dst = qbf; i = idx; }
    else           { src = kb; dst = kbf; i = idx - nq4; }
    float4 f = ((const float4*)src)[i];
    ushort4 u;
    u.x = bf16_of(f.x); u.y = bf16_of(f.y); u.z = bf16_of(f.z); u.w = bf16_of(f.w);
    ((ushort4*)dst)[i] = u;
}

// ---------------------------------------------------------------------------
// Transpose V (fp32 [seq][512]) -> vbt (bf16 [512 dim][2048 seq]).
// ---------------------------------------------------------------------------
__global__ __launch_bounds__(256) void transpose_v(const float* __restrict__ vb,
                                                   unsigned short* __restrict__ vbt) {
    __shared__ float tile[64][65];
    const int d0 = blockIdx.x * 64;
    const int s0 = blockIdx.y * 64;
    const int t = threadIdx.x;
#pragma unroll
    for (int i = 0; i < 16; i++) {
        int idx = t + i * 256;
        int r = idx >> 6, c = idx & 63;           // r: seq-local, c: dim-local
        tile[r][c] = vb[(size_t)(s0 + r) * KV_DIM + d0 + c];
    }
    __syncthreads();
#pragma unroll
    for (int i = 0; i < 16; i++) {
        int idx = t + i * 256;
        int r = idx >> 6, c = idx & 63;           // r: dim-local, c: seq-local
        vbt[(size_t)(d0 + r) * S_LEN + s0 + c] = bf16_of(tile[c][r]);
    }
}

// ---------------------------------------------------------------------------
// Flash attention, bf16 MFMA 16x16x32.  Block = (head, 64 Q rows), 4 waves.
// Wave w owns Q rows q0 + w*16 .. +15.  Iterates causal 64-key tiles.
// ---------------------------------------------------------------------------
__global__ __launch_bounds__(256) void attn_mfma(const unsigned short* __restrict__ qb,
                                                 const unsigned short* __restrict__ kb,
                                                 const unsigned short* __restrict__ vbt,
                                                 float* __restrict__ out) {
    const int h  = blockIdx.y;                    // 0..31
    const int qt = gridDim.x - 1 - blockIdx.x;    // long blocks dispatch first
    const int q0 = qt * 64;
    const int kh = h >> 2;
    const int tid  = threadIdx.x;
    const int wave = tid >> 6;
    const int lane = tid & 63;
    const int m16  = lane & 15;
    const int quad = lane >> 4;

    __shared__ unsigned short Ks[64][72];         // [seq][dim], stride 72 -> conflict-free b128
    __shared__ unsigned short Vt[64][72];         // [dim][seq]
    __shared__ unsigned short Ps[4][16][72];      // per-wave P: [qrow][seq]

    // Q A-frags: fixed for the whole block. A[m=lane&15][k=quad*8+j], k in {0..31},{32..63}
    bf16x8 qa[2];
    {
        const int qrow = q0 + wave * 16 + m16;
#pragma unroll
        for (int kb2 = 0; kb2 < 2; kb2++)
            qa[kb2] = *(const bf16x8*)&qb[(size_t)qrow * DIM + h * 64 + kb2 * 32 + quad * 8];
    }

    f32x4 o_acc[4];
#pragma unroll
    for (int nb = 0; nb < 4; nb++) o_acc[nb] = (f32x4){0.f, 0.f, 0.f, 0.f};
    float m_st[4], l_st[4];
#pragma unroll
    for (int r = 0; r < 4; r++) { m_st[r] = -1e30f; l_st[r] = 0.f; }

    const int qrow_base = q0 + wave * 16 + quad * 4;   // + r

    for (int kt = 0; kt <= qt; kt++) {
        // ---- stage K tile [64 seq][64 dim] and V^T tile [64 dim][64 seq] ----
#pragma unroll
        for (int i = 0; i < 2; i++) {
            int idx = tid + i * 256;                   // 0..511
            int r = idx >> 3, c8 = idx & 7;
            *(bf16x8*)&Ks[r][c8 * 8] =
                *(const bf16x8*)&kb[(size_t)(kt * 64 + r) * KV_DIM + kh * 64 + c8 * 8];
            *(bf16x8*)&Vt[r][c8 * 8] =
                *(const bf16x8*)&vbt[(size_t)(kh * 64 + r) * S_LEN + kt * 64 + c8 * 8];
        }
        __syncthreads();

        // ---- S = Q K^T : 8 MFMAs (4 col-blocks x 2 k-steps) ----
        f32x4 sc[4];
#pragma unroll
        for (int cb = 0; cb < 4; cb++) sc[cb] = (f32x4){0.f, 0.f, 0.f, 0.f};
#pragma unroll
        for (int kb2 = 0; kb2 < 2; kb2++) {
#pragma unroll
            for (int cb = 0; cb < 4; cb++) {
                bf16x8 kf = *(const bf16x8*)&Ks[cb * 16 + m16][kb2 * 32 + quad * 8];
                sc[cb] = __builtin_amdgcn_mfma_f32_16x16x32_bf16(qa[kb2], kf, sc[cb], 0, 0, 0);
            }
        }

        // ---- scale + causal mask (diagonal tile only) ----
#pragma unroll
        for (int cb = 0; cb < 4; cb++)
#pragma unroll
            for (int r = 0; r < 4; r++) sc[cb][r] *= 0.125f;
        if (kt == qt) {
#pragma unroll
            for (int cb = 0; cb < 4; cb++) {
                int key = kt * 64 + cb * 16 + m16;
#pragma unroll
                for (int r = 0; r < 4; r++)
                    if (key > qrow_base + r) sc[cb][r] = -1e30f;
            }
        }

        // ---- online softmax: row stats via shuffle over 16-lane column group ----
        float rmax[4];
#pragma unroll
        for (int r = 0; r < 4; r++)
            rmax[r] = fmaxf(fmaxf(sc[0][r], sc[1][r]), fmaxf(sc[2][r], sc[3][r]));
#pragma unroll
        for (int off = 1; off < 16; off <<= 1)
#pragma unroll
            for (int r = 0; r < 4; r++)
                rmax[r] = fmaxf(rmax[r], __shfl_xor(rmax[r], off, 64));

        float alpha[4];
#pragma unroll
        for (int r = 0; r < 4; r++) {
            float mnew = fmaxf(m_st[r], rmax[r]);
            alpha[r] = __expf(m_st[r] - mnew);
            m_st[r] = mnew;
        }
        float rsum[4] = {0.f, 0.f, 0.f, 0.f};
#pragma unroll
        for (int cb = 0; cb < 4; cb++)
#pragma unroll
            for (int r = 0; r < 4; r++) {
                float p = __expf(sc[cb][r] - m_st[r]);
                sc[cb][r] = p;
                rsum[r] += p;
            }
#pragma unroll
        for (int off = 1; off < 16; off <<= 1)
#pragma unroll
            for (int r = 0; r < 4; r++)
                rsum[r] += __shfl_xor(rsum[r], off, 64);
#pragma unroll
        for (int r = 0; r < 4; r++) l_st[r] = l_st[r] * alpha[r] + rsum[r];

        // ---- P: C-layout regs -> LDS [qrow][seq] (A-operand layout source) ----
#pragma unroll
        for (int cb = 0; cb < 4; cb++)
#pragma unroll
            for (int r = 0; r < 4; r++)
                Ps[wave][quad * 4 + r][cb * 16 + m16] = bf16_of(sc[cb][r]);

        // ---- rescale O ----
#pragma unroll
        for (int nb = 0; nb < 4; nb++)
#pragma unroll
            for (int r = 0; r < 4; r++) o_acc[nb][r] *= alpha[r];

        // ---- O += P V : 8 MFMAs ----
#pragma unroll
        for (int kb2 = 0; kb2 < 2; kb2++) {
            bf16x8 pa = *(const bf16x8*)&Ps[wave][m16][kb2 * 32 + quad * 8];
#pragma unroll
            for (int nb = 0; nb < 4; nb++) {
                bf16x8 vf = *(const bf16x8*)&Vt[nb * 16 + m16][kb2 * 32 + quad * 8];
                o_acc[nb] = __builtin_amdgcn_mfma_f32_16x16x32_bf16(pa, vf, o_acc[nb], 0, 0, 0);
            }
        }
        __syncthreads();
    }

    // ---- epilogue: divide by l, store fp32 ----
#pragma unroll
    for (int r = 0; r < 4; r++) {
        float inv_l = 1.f / l_st[r];
#pragma unroll
        for (int nb = 0; nb < 4; nb++)
            out[(size_t)(qrow_base + r) * DIM + h * 64 + nb * 16 + m16] = o_acc[nb][r] * inv_l;
    }
}

// ---------------------------------------------------------------------------
extern "C" void kernel_launch(void* const* d_in, const int* in_sizes, int n_in,
                              void* d_out, int out_size, void* d_ws, size_t ws_size,
                              hipStream_t stream) {
    const float* x    = (const float*)d_in[0];
    const float* wq   = (const float*)d_in[1];
    const float* wk   = (const float*)d_in[2];
    const float* wv   = (const float*)d_in[3];
    const float* wo   = (const float*)d_in[4];
    const float* fcos = (const float*)d_in[5];
    const float* fsin = (const float*)d_in[6];

    float* qb = (float*)d_ws;                              // 16MB (reused as attn out)
    float* kb = qb + (size_t)S_LEN * DIM;                  // 4MB
    float* vb = kb + (size_t)S_LEN * KV_DIM;               // 4MB
    unsigned short* qbf = (unsigned short*)(vb + (size_t)S_LEN * KV_DIM);  // 8MB
    unsigned short* kbf = qbf + (size_t)S_LEN * DIM;       // 2MB
    unsigned short* vbt = kbf + (size_t)S_LEN * KV_DIM;    // 2MB
    float* attn = qb;   // alias: fp32 q dead after convert_qk

    // QKV projections (fp32)
    gemm_tile<<<dim3(DIM / 64, S_LEN / 64), 256, 0, stream>>>(x, wq, qb, S_LEN, DIM, DIM);
    gemm_tile<<<dim3(KV_DIM / 64, S_LEN / 64), 256, 0, stream>>>(x, wk, kb, S_LEN, KV_DIM, DIM);
    gemm_tile<<<dim3(KV_DIM / 64, S_LEN / 64), 256, 0, stream>>>(x, wv, vb, S_LEN, KV_DIM, DIM);

    // RoPE on q,k
    int total_pairs = S_LEN * N_HEADS * 32 + S_LEN * N_KV_HEADS * 32;
    rope_kernel<<<total_pairs / 256, 256, 0, stream>>>(qb, kb, fcos, fsin);

    // bf16 conversions: q,k straight; v transposed to [dim][seq]
    convert_qk<<<(S_LEN * DIM / 4 + S_LEN * KV_DIM / 4) / 256, 256, 0, stream>>>(qb, kb, qbf, kbf);
    transpose_v<<<dim3(KV_DIM / 64, S_LEN / 64), 256, 0, stream>>>(vb, vbt);

    // flash attention (bf16 MFMA)
    attn_mfma<<<dim3(S_LEN / 64, N_HEADS), 256, 0, stream>>>(qbf, kbf, vbt, attn);

    // output projection (fp32)
    gemm_tile<<<dim3(DIM / 64, S_LEN / 64), 256, 0, stream>>>(attn, wo, (float*)d_out, S_LEN, DIM, DIM);
}

// Round 3
// 388.690 us; speedup vs baseline: 5.1642x; 2.7512x over previous
//
#include <hip/hip_runtime.h>
#include <hip/hip_bf16.h>

#define DIM 2048
#define S_LEN 2048
#define N_HEADS 32
#define N_KV_HEADS 8
#define HEAD_DIM 64
#define KV_DIM (N_KV_HEADS * HEAD_DIM)   // 512
#define QKV_N (DIM + 2 * KV_DIM)         // 3072

typedef __attribute__((ext_vector_type(8))) short bf16x8;
typedef __attribute__((ext_vector_type(4))) float f32x4;

__device__ __forceinline__ unsigned short bf16_of(float f) {
    __hip_bfloat16 h = __float2bfloat16(f);
    return *reinterpret_cast<unsigned short*>(&h);
}
__device__ __forceinline__ float f_of_bf16(unsigned short u) {
    unsigned int x = ((unsigned int)u) << 16;
    return __uint_as_float(x);
}
__device__ __forceinline__ void gl_lds16(const void* g, void* l) {
    __builtin_amdgcn_global_load_lds((const __attribute__((address_space(1))) void*)g,
                                     (__attribute__((address_space(3))) void*)l, 16, 0, 0);
}

// ---------------------------------------------------------------------------
// x (fp32) -> bf16, straight layout.
// ---------------------------------------------------------------------------
__global__ __launch_bounds__(256) void convert_x(const float* __restrict__ src,
                                                 unsigned short* __restrict__ dst) {
    int idx = blockIdx.x * 256 + threadIdx.x;
    float4 f = ((const float4*)src)[idx];
    ushort4 u;
    u.x = bf16_of(f.x); u.y = bf16_of(f.y); u.z = bf16_of(f.z); u.w = bf16_of(f.w);
    ((ushort4*)dst)[idx] = u;
}

// ---------------------------------------------------------------------------
// Transpose + convert: src fp32 [rows][cols] -> dst bf16 [cols][dst_stride],
// dst[c][r] = src[r][c].  Grid (cols/64, rows/64).
// ---------------------------------------------------------------------------
__global__ __launch_bounds__(256) void transpose_cvt(const float* __restrict__ src,
                                                     unsigned short* __restrict__ dst,
                                                     int src_cols, int dst_stride) {
    __shared__ float tile[64][65];
    const int c0 = blockIdx.x * 64;
    const int r0 = blockIdx.y * 64;
    const int t = threadIdx.x;
#pragma unroll
    for (int i = 0; i < 16; i++) {
        int idx = t + i * 256;
        int r = idx >> 6, c = idx & 63;
        tile[r][c] = src[(size_t)(r0 + r) * src_cols + c0 + c];
    }
    __syncthreads();
#pragma unroll
    for (int i = 0; i < 16; i++) {
        int idx = t + i * 256;
        int r = idx >> 6, c = idx & 63;
        dst[(size_t)(c0 + r) * dst_stride + r0 + c] = bf16_of(tile[c][r]);
    }
}

// ---------------------------------------------------------------------------
// bf16 MFMA GEMM (m97-style): C[M][N] = A[M][K] @ Bt[N][K]^T.
// 128x128 tile, BK=64, 4 waves (each 64x64), global_load_lds 16B staging,
// XOR chunk swizzle for conflict-free ds_read_b128.  c_bf16: output dtype.
// ---------------------------------------------------------------------------
__global__ __launch_bounds__(256) void gemm_bt(const unsigned short* __restrict__ A,
                                               const unsigned short* __restrict__ Bt,
                                               void* __restrict__ Cv,
                                               int M, int N, int K, int c_bf16) {
    __shared__ unsigned short As[128 * 64];
    __shared__ unsigned short Bs[128 * 64];
    const int tid = threadIdx.x;
    const int wave = tid >> 6, lane = tid & 63;
    const int m16 = lane & 15, quad = lane >> 4;
    const int m0 = blockIdx.y * 128, n0 = blockIdx.x * 128;
    const int wm = (wave >> 1) * 64, wn = (wave & 1) * 64;

    // staging: lane covers row (g*32 + wave*8 + lane/8), chunk (lane&7) swizzled
    const int lrow = lane >> 3;
    const int gc = (lane & 7) ^ lrow;            // row&7 == lrow for all g
    const unsigned short* Ab = A + (size_t)(m0 + wave * 8 + lrow) * K + gc * 8;
    const unsigned short* Bb = Bt + (size_t)(n0 + wave * 8 + lrow) * K + gc * 8;

    f32x4 acc[4][4];
#pragma unroll
    for (int mb = 0; mb < 4; mb++)
#pragma unroll
        for (int nb = 0; nb < 4; nb++) acc[mb][nb] = (f32x4){0.f, 0.f, 0.f, 0.f};

    for (int k0 = 0; k0 < K; k0 += 64) {
#pragma unroll
        for (int g = 0; g < 4; g++) {
            gl_lds16(Ab + (size_t)g * 32 * K + k0, &As[(g * 32 + wave * 8) * 64]);
            gl_lds16(Bb + (size_t)g * 32 * K + k0, &Bs[(g * 32 + wave * 8) * 64]);
        }
        __syncthreads();
#pragma unroll
        for (int ks = 0; ks < 2; ks++) {
            bf16x8 af[4], bfr[4];
#pragma unroll
            for (int mb = 0; mb < 4; mb++) {
                int row = wm + mb * 16 + m16;
                int ch = (ks * 4 + quad) ^ (m16 & 7);
                af[mb] = *(const bf16x8*)&As[row * 64 + ch * 8];
                int rowb = wn + mb * 16 + m16;
                bfr[mb] = *(const bf16x8*)&Bs[rowb * 64 + ch * 8];
            }
#pragma unroll
            for (int mb = 0; mb < 4; mb++)
#pragma unroll
                for (int nb = 0; nb < 4; nb++)
                    acc[mb][nb] = __builtin_amdgcn_mfma_f32_16x16x32_bf16(af[mb], bfr[nb], acc[mb][nb], 0, 0, 0);
        }
        __syncthreads();
    }

    if (c_bf16) {
        unsigned short* C = (unsigned short*)Cv;
#pragma unroll
        for (int mb = 0; mb < 4; mb++)
#pragma unroll
            for (int nb = 0; nb < 4; nb++)
#pragma unroll
                for (int r = 0; r < 4; r++)
                    C[(size_t)(m0 + wm + mb * 16 + quad * 4 + r) * N + n0 + wn + nb * 16 + m16] =
                        bf16_of(acc[mb][nb][r]);
    } else {
        float* C = (float*)Cv;
#pragma unroll
        for (int mb = 0; mb < 4; mb++)
#pragma unroll
            for (int nb = 0; nb < 4; nb++)
#pragma unroll
                for (int r = 0; r < 4; r++)
                    C[(size_t)(m0 + wm + mb * 16 + quad * 4 + r) * N + n0 + wn + nb * 16 + m16] =
                        acc[mb][nb][r];
    }
}

// ---------------------------------------------------------------------------
// RoPE: read bf16 qkv [S][3072], rotate in fp32, write bf16 q [S][2048],
// k [S][512].  One thread = 4 pairs (8 elems, 16B).
// ---------------------------------------------------------------------------
__global__ __launch_bounds__(256) void rope_bf16(const unsigned short* __restrict__ qkv,
                                                 unsigned short* __restrict__ qbf,
                                                 unsigned short* __restrict__ kbf,
                                                 const float* __restrict__ fcos,
                                                 const float* __restrict__ fsin) {
    int idx = blockIdx.x * 256 + threadIdx.x;
    const int nq = S_LEN * N_HEADS * 8;          // q chunks
    int s, j, srcoff, dstoff;
    unsigned short* dst;
    if (idx < nq) {
        s = idx >> 8;                            // 32 heads * 8 chunks
        int rem = idx & 255;
        int h = rem >> 3;
        j = rem & 7;
        srcoff = s * QKV_N + h * 64 + j * 8;
        dstoff = s * DIM + h * 64 + j * 8;
        dst = qbf;
    } else {
        int t2 = idx - nq;
        s = t2 >> 6;                             // 8 heads * 8 chunks
        int rem = t2 & 63;
        int h = rem >> 3;
        j = rem & 7;
        srcoff = s * QKV_N + DIM + h * 64 + j * 8;
        dstoff = s * KV_DIM + h * 64 + j * 8;
        dst = kbf;
    }
    bf16x8 v8 = *(const bf16x8*)&qkv[srcoff];
    float4 c4 = *(const float4*)&fcos[s * 32 + j * 4];
    float4 s4 = *(const float4*)&fsin[s * 32 + j * 4];
    float cs[4] = {c4.x, c4.y, c4.z, c4.w};
    float sn[4] = {s4.x, s4.y, s4.z, s4.w};
    bf16x8 o;
#pragma unroll
    for (int p = 0; p < 4; p++) {
        float a = f_of_bf16((unsigned short)v8[2 * p]);
        float b = f_of_bf16((unsigned short)v8[2 * p + 1]);
        o[2 * p]     = (short)bf16_of(a * cs[p] - b * sn[p]);
        o[2 * p + 1] = (short)bf16_of(a * sn[p] + b * cs[p]);
    }
    *(bf16x8*)&dst[dstoff] = o;
}

// ---------------------------------------------------------------------------
// Transpose V slice of qkv (bf16 [S][3072], cols 2560..3071) -> vbt [512][2048].
// ---------------------------------------------------------------------------
__global__ __launch_bounds__(256) void transpose_v_bf16(const unsigned short* __restrict__ qkv,
                                                        unsigned short* __restrict__ vbt) {
    __shared__ unsigned short tile[64][65];
    const int d0 = blockIdx.x * 64;
    const int s0 = blockIdx.y * 64;
    const int t = threadIdx.x;
#pragma unroll
    for (int i = 0; i < 16; i++) {
        int idx = t + i * 256;
        int r = idx >> 6, c = idx & 63;          // r: seq-local, c: dim-local
        tile[r][c] = qkv[(size_t)(s0 + r) * QKV_N + DIM + KV_DIM + d0 + c];
    }
    __syncthreads();
#pragma unroll
    for (int i = 0; i < 16; i++) {
        int idx = t + i * 256;
        int r = idx >> 6, c = idx & 63;          // r: dim-local, c: seq-local
        vbt[(size_t)(d0 + r) * S_LEN + s0 + c] = tile[c][r];
    }
}

// ---------------------------------------------------------------------------
// Flash attention, bf16 MFMA 16x16x32.  Block = (head, 64 Q rows), 4 waves.
// Output bf16 for the out-projection.
// ---------------------------------------------------------------------------
__global__ __launch_bounds__(256) void attn_mfma(const unsigned short* __restrict__ qb,
                                                 const unsigned short* __restrict__ kb,
                                                 const unsigned short* __restrict__ vbt,
                                                 unsigned short* __restrict__ out) {
    const int h  = blockIdx.y;
    const int qt = gridDim.x - 1 - blockIdx.x;   // long blocks dispatch first
    const int q0 = qt * 64;
    const int kh = h >> 2;
    const int tid  = threadIdx.x;
    const int wave = tid >> 6;
    const int lane = tid & 63;
    const int m16  = lane & 15;
    const int quad = lane >> 4;

    __shared__ unsigned short Ks[64][72];
    __shared__ unsigned short Vt[64][72];
    __shared__ unsigned short Ps[4][16][72];

    bf16x8 qa[2];
    {
        const int qrow = q0 + wave * 16 + m16;
#pragma unroll
        for (int kb2 = 0; kb2 < 2; kb2++)
            qa[kb2] = *(const bf16x8*)&qb[(size_t)qrow * DIM + h * 64 + kb2 * 32 + quad * 8];
    }

    f32x4 o_acc[4];
#pragma unroll
    for (int nb = 0; nb < 4; nb++) o_acc[nb] = (f32x4){0.f, 0.f, 0.f, 0.f};
    float m_st[4], l_st[4];
#pragma unroll
    for (int r = 0; r < 4; r++) { m_st[r] = -1e30f; l_st[r] = 0.f; }

    const int qrow_base = q0 + wave * 16 + quad * 4;

    for (int kt = 0; kt <= qt; kt++) {
#pragma unroll
        for (int i = 0; i < 2; i++) {
            int idx = tid + i * 256;
            int r = idx >> 3, c8 = idx & 7;
            *(bf16x8*)&Ks[r][c8 * 8] =
                *(const bf16x8*)&kb[(size_t)(kt * 64 + r) * KV_DIM + kh * 64 + c8 * 8];
            *(bf16x8*)&Vt[r][c8 * 8] =
                *(const bf16x8*)&vbt[(size_t)(kh * 64 + r) * S_LEN + kt * 64 + c8 * 8];
        }
        __syncthreads();

        f32x4 sc[4];
#pragma unroll
        for (int cb = 0; cb < 4; cb++) sc[cb] = (f32x4){0.f, 0.f, 0.f, 0.f};
#pragma unroll
        for (int kb2 = 0; kb2 < 2; kb2++) {
#pragma unroll
            for (int cb = 0; cb < 4; cb++) {
                bf16x8 kf = *(const bf16x8*)&Ks[cb * 16 + m16][kb2 * 32 + quad * 8];
                sc[cb] = __builtin_amdgcn_mfma_f32_16x16x32_bf16(qa[kb2], kf, sc[cb], 0, 0, 0);
            }
        }

#pragma unroll
        for (int cb = 0; cb < 4; cb++)
#pragma unroll
            for (int r = 0; r < 4; r++) sc[cb][r] *= 0.125f;
        if (kt == qt) {
#pragma unroll
            for (int cb = 0; cb < 4; cb++) {
                int key = kt * 64 + cb * 16 + m16;
#pragma unroll
                for (int r = 0; r < 4; r++)
                    if (key > qrow_base + r) sc[cb][r] = -1e30f;
            }
        }

        float rmax[4];
#pragma unroll
        for (int r = 0; r < 4; r++)
            rmax[r] = fmaxf(fmaxf(sc[0][r], sc[1][r]), fmaxf(sc[2][r], sc[3][r]));
#pragma unroll
        for (int off = 1; off < 16; off <<= 1)
#pragma unroll
            for (int r = 0; r < 4; r++)
                rmax[r] = fmaxf(rmax[r], __shfl_xor(rmax[r], off, 64));

        float alpha[4];
#pragma unroll
        for (int r = 0; r < 4; r++) {
            float mnew = fmaxf(m_st[r], rmax[r]);
            alpha[r] = __expf(m_st[r] - mnew);
            m_st[r] = mnew;
        }
        float rsum[4] = {0.f, 0.f, 0.f, 0.f};
#pragma unroll
        for (int cb = 0; cb < 4; cb++)
#pragma unroll
            for (int r = 0; r < 4; r++) {
                float p = __expf(sc[cb][r] - m_st[r]);
                sc[cb][r] = p;
                rsum[r] += p;
            }
#pragma unroll
        for (int off = 1; off < 16; off <<= 1)
#pragma unroll
            for (int r = 0; r < 4; r++)
                rsum[r] += __shfl_xor(rsum[r], off, 64);
#pragma unroll
        for (int r = 0; r < 4; r++) l_st[r] = l_st[r] * alpha[r] + rsum[r];

#pragma unroll
        for (int cb = 0; cb < 4; cb++)
#pragma unroll
            for (int r = 0; r < 4; r++)
                Ps[wave][quad * 4 + r][cb * 16 + m16] = bf16_of(sc[cb][r]);

#pragma unroll
        for (int nb = 0; nb < 4; nb++)
#pragma unroll
            for (int r = 0; r < 4; r++) o_acc[nb][r] *= alpha[r];

#pragma unroll
        for (int kb2 = 0; kb2 < 2; kb2++) {
            bf16x8 pa = *(const bf16x8*)&Ps[wave][m16][kb2 * 32 + quad * 8];
#pragma unroll
            for (int nb = 0; nb < 4; nb++) {
                bf16x8 vf = *(const bf16x8*)&Vt[nb * 16 + m16][kb2 * 32 + quad * 8];
                o_acc[nb] = __builtin_amdgcn_mfma_f32_16x16x32_bf16(pa, vf, o_acc[nb], 0, 0, 0);
            }
        }
        __syncthreads();
    }

#pragma unroll
    for (int r = 0; r < 4; r++) {
        float inv_l = 1.f / l_st[r];
#pragma unroll
        for (int nb = 0; nb < 4; nb++)
            out[(size_t)(qrow_base + r) * DIM + h * 64 + nb * 16 + m16] =
                bf16_of(o_acc[nb][r] * inv_l);
    }
}

// ---------------------------------------------------------------------------
extern "C" void kernel_launch(void* const* d_in, const int* in_sizes, int n_in,
                              void* d_out, int out_size, void* d_ws, size_t ws_size,
                              hipStream_t stream) {
    const float* x    = (const float*)d_in[0];
    const float* wq   = (const float*)d_in[1];
    const float* wk   = (const float*)d_in[2];
    const float* wv   = (const float*)d_in[3];
    const float* wo   = (const float*)d_in[4];
    const float* fcos = (const float*)d_in[5];
    const float* fsin = (const float*)d_in[6];

    char* ws = (char*)d_ws;
    const size_t MB = 1024 * 1024;
    unsigned short* xbf    = (unsigned short*)(ws);            //  8 MB [2048][2048]
    unsigned short* wqkvT  = (unsigned short*)(ws + 8 * MB);   // 12 MB [3072][2048]
    unsigned short* woT    = (unsigned short*)(ws + 20 * MB);  //  8 MB [2048][2048]
    unsigned short* qkvbf  = (unsigned short*)(ws + 28 * MB);  // 12 MB [2048][3072]
    unsigned short* vbt    = (unsigned short*)(ws + 40 * MB);  //  2 MB [512][2048]
    // aliases (producer runs strictly after the aliased buffer is dead):
    unsigned short* qbf    = (unsigned short*)(ws + 8 * MB);   //  8 MB (over wqkvT)
    unsigned short* kbf    = (unsigned short*)(ws + 16 * MB);  //  2 MB (over wqkvT tail)
    unsigned short* attnbf = (unsigned short*)(ws);            //  8 MB (over xbf)

    // bf16 conversions / weight transposes
    convert_x<<<(DIM * S_LEN / 4) / 256, 256, 0, stream>>>(x, xbf);
    transpose_cvt<<<dim3(32, 32), 256, 0, stream>>>(wq, wqkvT, DIM, DIM);
    transpose_cvt<<<dim3(8, 32), 256, 0, stream>>>(wk, wqkvT + (size_t)DIM * DIM, KV_DIM, DIM);
    transpose_cvt<<<dim3(8, 32), 256, 0, stream>>>(wv, wqkvT + (size_t)(DIM + KV_DIM) * DIM, KV_DIM, DIM);
    transpose_cvt<<<dim3(32, 32), 256, 0, stream>>>(wo, woT, DIM, DIM);

    // fused QKV projection (bf16 out)
    gemm_bt<<<dim3(QKV_N / 128, S_LEN / 128), 256, 0, stream>>>(xbf, wqkvT, qkvbf,
                                                                S_LEN, QKV_N, DIM, 1);

    // RoPE -> qbf, kbf (bf16)
    int n_chunks = S_LEN * N_HEADS * 8 + S_LEN * N_KV_HEADS * 8;   // 655360
    rope_bf16<<<n_chunks / 256, 256, 0, stream>>>(qkvbf, qbf, kbf, fcos, fsin);

    // V transpose -> vbt [dim][seq]
    transpose_v_bf16<<<dim3(KV_DIM / 64, S_LEN / 64), 256, 0, stream>>>(qkvbf, vbt);

    // flash attention (bf16 out)
    attn_mfma<<<dim3(S_LEN / 64, N_HEADS), 256, 0, stream>>>(qbf, kbf, vbt, attnbf);

    // output projection (fp32 out)
    gemm_bt<<<dim3(DIM / 128, S_LEN / 128), 256, 0, stream>>>(attnbf, woT, d_out,
                                                              S_LEN, DIM, DIM, 0);
}

// Round 4
// 270.755 us; speedup vs baseline: 7.4136x; 1.4356x over previous
//
#include <hip/hip_runtime.h>
#include <hip/hip_bf16.h>

#define DIM 2048
#define S_LEN 2048
#define N_HEADS 32
#define N_KV_HEADS 8
#define HEAD_DIM 64
#define KV_DIM (N_KV_HEADS * HEAD_DIM)   // 512
#define QKV_N (DIM + 2 * KV_DIM)         // 3072

typedef __attribute__((ext_vector_type(8))) short bf16x8;
typedef __attribute__((ext_vector_type(4))) float f32x4;

__device__ __forceinline__ unsigned short bf16_of(float f) {
    __hip_bfloat16 h = __float2bfloat16(f);
    return *reinterpret_cast<unsigned short*>(&h);
}
__device__ __forceinline__ float f_of_bf16(unsigned short u) {
    unsigned int x = ((unsigned int)u) << 16;
    return __uint_as_float(x);
}
__device__ __forceinline__ void gl_lds16(const void* g, void* l) {
    __builtin_amdgcn_global_load_lds((const __attribute__((address_space(1))) void*)g,
                                     (__attribute__((address_space(3))) void*)l, 16, 0, 0);
}

// ---------------------------------------------------------------------------
// x (fp32) -> bf16, straight layout.
// ---------------------------------------------------------------------------
__global__ __launch_bounds__(256) void convert_x(const float* __restrict__ src,
                                                 unsigned short* __restrict__ dst) {
    int idx = blockIdx.x * 256 + threadIdx.x;
    float4 f = ((const float4*)src)[idx];
    ushort4 u;
    u.x = bf16_of(f.x); u.y = bf16_of(f.y); u.z = bf16_of(f.z); u.w = bf16_of(f.w);
    ((ushort4*)dst)[idx] = u;
}

// ---------------------------------------------------------------------------
// Transpose + convert: src fp32 [rows][cols] -> dst bf16 [cols][dst_stride].
// ---------------------------------------------------------------------------
__global__ __launch_bounds__(256) void transpose_cvt(const float* __restrict__ src,
                                                     unsigned short* __restrict__ dst,
                                                     int src_cols, int dst_stride) {
    __shared__ float tile[64][65];
    const int c0 = blockIdx.x * 64;
    const int r0 = blockIdx.y * 64;
    const int t = threadIdx.x;
#pragma unroll
    for (int i = 0; i < 16; i++) {
        int idx = t + i * 256;
        int r = idx >> 6, c = idx & 63;
        tile[r][c] = src[(size_t)(r0 + r) * src_cols + c0 + c];
    }
    __syncthreads();
#pragma unroll
    for (int i = 0; i < 16; i++) {
        int idx = t + i * 256;
        int r = idx >> 6, c = idx & 63;
        dst[(size_t)(c0 + r) * dst_stride + r0 + c] = bf16_of(tile[c][r]);
    }
}

// ---------------------------------------------------------------------------
// bf16 MFMA GEMM (m97-style): C[M][N] = A[M][K] @ Bt[N][K]^T.
// ---------------------------------------------------------------------------
__global__ __launch_bounds__(256) void gemm_bt(const unsigned short* __restrict__ A,
                                               const unsigned short* __restrict__ Bt,
                                               void* __restrict__ Cv,
                                               int M, int N, int K, int c_bf16) {
    __shared__ unsigned short As[128 * 64];
    __shared__ unsigned short Bs[128 * 64];
    const int tid = threadIdx.x;
    const int wave = tid >> 6, lane = tid & 63;
    const int m16 = lane & 15, quad = lane >> 4;
    const int m0 = blockIdx.y * 128, n0 = blockIdx.x * 128;
    const int wm = (wave >> 1) * 64, wn = (wave & 1) * 64;

    const int lrow = lane >> 3;
    const int gc = (lane & 7) ^ lrow;
    const unsigned short* Ab = A + (size_t)(m0 + wave * 8 + lrow) * K + gc * 8;
    const unsigned short* Bb = Bt + (size_t)(n0 + wave * 8 + lrow) * K + gc * 8;

    f32x4 acc[4][4];
#pragma unroll
    for (int mb = 0; mb < 4; mb++)
#pragma unroll
        for (int nb = 0; nb < 4; nb++) acc[mb][nb] = (f32x4){0.f, 0.f, 0.f, 0.f};

    for (int k0 = 0; k0 < K; k0 += 64) {
#pragma unroll
        for (int g = 0; g < 4; g++) {
            gl_lds16(Ab + (size_t)g * 32 * K + k0, &As[(g * 32 + wave * 8) * 64]);
            gl_lds16(Bb + (size_t)g * 32 * K + k0, &Bs[(g * 32 + wave * 8) * 64]);
        }
        __syncthreads();
#pragma unroll
        for (int ks = 0; ks < 2; ks++) {
            bf16x8 af[4], bfr[4];
#pragma unroll
            for (int mb = 0; mb < 4; mb++) {
                int row = wm + mb * 16 + m16;
                int ch = (ks * 4 + quad) ^ (m16 & 7);
                af[mb] = *(const bf16x8*)&As[row * 64 + ch * 8];
                int rowb = wn + mb * 16 + m16;
                bfr[mb] = *(const bf16x8*)&Bs[rowb * 64 + ch * 8];
            }
#pragma unroll
            for (int mb = 0; mb < 4; mb++)
#pragma unroll
                for (int nb = 0; nb < 4; nb++)
                    acc[mb][nb] = __builtin_amdgcn_mfma_f32_16x16x32_bf16(af[mb], bfr[nb], acc[mb][nb], 0, 0, 0);
        }
        __syncthreads();
    }

    if (c_bf16) {
        unsigned short* C = (unsigned short*)Cv;
#pragma unroll
        for (int mb = 0; mb < 4; mb++)
#pragma unroll
            for (int nb = 0; nb < 4; nb++)
#pragma unroll
                for (int r = 0; r < 4; r++)
                    C[(size_t)(m0 + wm + mb * 16 + quad * 4 + r) * N + n0 + wn + nb * 16 + m16] =
                        bf16_of(acc[mb][nb][r]);
    } else {
        float* C = (float*)Cv;
#pragma unroll
        for (int mb = 0; mb < 4; mb++)
#pragma unroll
            for (int nb = 0; nb < 4; nb++)
#pragma unroll
                for (int r = 0; r < 4; r++)
                    C[(size_t)(m0 + wm + mb * 16 + quad * 4 + r) * N + n0 + wn + nb * 16 + m16] =
                        acc[mb][nb][r];
    }
}

// ---------------------------------------------------------------------------
// RoPE: read bf16 qkv [S][3072], rotate in fp32, write bf16 q/k.
// ---------------------------------------------------------------------------
__global__ __launch_bounds__(256) void rope_bf16(const unsigned short* __restrict__ qkv,
                                                 unsigned short* __restrict__ qbf,
                                                 unsigned short* __restrict__ kbf,
                                                 const float* __restrict__ fcos,
                                                 const float* __restrict__ fsin) {
    int idx = blockIdx.x * 256 + threadIdx.x;
    const int nq = S_LEN * N_HEADS * 8;
    int s, j, srcoff, dstoff;
    unsigned short* dst;
    if (idx < nq) {
        s = idx >> 8;
        int rem = idx & 255;
        int h = rem >> 3;
        j = rem & 7;
        srcoff = s * QKV_N + h * 64 + j * 8;
        dstoff = s * DIM + h * 64 + j * 8;
        dst = qbf;
    } else {
        int t2 = idx - nq;
        s = t2 >> 6;
        int rem = t2 & 63;
        int h = rem >> 3;
        j = rem & 7;
        srcoff = s * QKV_N + DIM + h * 64 + j * 8;
        dstoff = s * KV_DIM + h * 64 + j * 8;
        dst = kbf;
    }
    bf16x8 v8 = *(const bf16x8*)&qkv[srcoff];
    float4 c4 = *(const float4*)&fcos[s * 32 + j * 4];
    float4 s4 = *(const float4*)&fsin[s * 32 + j * 4];
    float cs[4] = {c4.x, c4.y, c4.z, c4.w};
    float sn[4] = {s4.x, s4.y, s4.z, s4.w};
    bf16x8 o;
#pragma unroll
    for (int p = 0; p < 4; p++) {
        float a = f_of_bf16((unsigned short)v8[2 * p]);
        float b = f_of_bf16((unsigned short)v8[2 * p + 1]);
        o[2 * p]     = (short)bf16_of(a * cs[p] - b * sn[p]);
        o[2 * p + 1] = (short)bf16_of(a * sn[p] + b * cs[p]);
    }
    *(bf16x8*)&dst[dstoff] = o;
}

// ---------------------------------------------------------------------------
// Transpose V slice of qkv (bf16 [S][3072], cols 2560..3071) -> vbt [512][2048].
// ---------------------------------------------------------------------------
__global__ __launch_bounds__(256) void transpose_v_bf16(const unsigned short* __restrict__ qkv,
                                                        unsigned short* __restrict__ vbt) {
    __shared__ unsigned short tile[64][65];
    const int d0 = blockIdx.x * 64;
    const int s0 = blockIdx.y * 64;
    const int t = threadIdx.x;
#pragma unroll
    for (int i = 0; i < 16; i++) {
        int idx = t + i * 256;
        int r = idx >> 6, c = idx & 63;
        tile[r][c] = qkv[(size_t)(s0 + r) * QKV_N + DIM + KV_DIM + d0 + c];
    }
    __syncthreads();
#pragma unroll
    for (int i = 0; i < 16; i++) {
        int idx = t + i * 256;
        int r = idx >> 6, c = idx & 63;
        vbt[(size_t)(d0 + r) * S_LEN + s0 + c] = tile[c][r];
    }
}

// ---------------------------------------------------------------------------
// Flash attention v2: bf16 MFMA 16x16x32.
// Block = (head, PAIR of 64-row Q tiles: qt=31-bx then qt=bx) -> 17 K-tile
// iterations per block, uniform.  K-tile = 128 keys.  4 waves, wave = 16 Q rows.
// K/V staged via global_load_lds (width 16) with m97 XOR chunk swizzle.
// ---------------------------------------------------------------------------
__global__ __launch_bounds__(256) void attn_mfma2(const unsigned short* __restrict__ qb,
                                                  const unsigned short* __restrict__ kb,
                                                  const unsigned short* __restrict__ vbt,
                                                  unsigned short* __restrict__ out) {
    const int h  = blockIdx.y;
    const int bx = blockIdx.x;                    // 0..15
    const int kh = h >> 2;
    const int tid  = threadIdx.x;
    const int wave = tid >> 6;
    const int lane = tid & 63;
    const int m16  = lane & 15;
    const int quad = lane >> 4;

    __shared__ unsigned short Ks[128 * 64];       // [key][dim], swizzled chunks
    __shared__ unsigned short Vt[64 * 128];       // [dim][seq], swizzled chunks
    __shared__ unsigned short Ps[4][16 * 136];    // per-wave P [qrow][key]

    // staging lane decomposition
    const int lrow8 = lane >> 3;                  // K: 8 rows / wave-issue
    const int kc    = (lane & 7) ^ lrow8;         // K global chunk (swizzle)
    const int lrow4 = lane >> 4;                  // V: 4 rows / wave-issue
    const int vc    = (lane & 15) ^ ((wave * 4 + lrow4) & 7);  // V global chunk

    const unsigned short* Kbase = kb + (size_t)kh * 64 + (size_t)(wave * 8 + lrow8) * KV_DIM + kc * 8;
    const unsigned short* Vbase = vbt + (size_t)(kh * 64 + wave * 4 + lrow4) * S_LEN + vc * 8;

#pragma unroll
    for (int half = 0; half < 2; half++) {
        const int qt = half ? bx : (31 - bx);
        const int q0 = qt * 64;
        const int n_iter = (qt >> 1) + 1;

        // Q A-frags for this q-tile
        bf16x8 qa[2];
        {
            const int qrow = q0 + wave * 16 + m16;
#pragma unroll
            for (int ks = 0; ks < 2; ks++)
                qa[ks] = *(const bf16x8*)&qb[(size_t)qrow * DIM + h * 64 + ks * 32 + quad * 8];
        }

        f32x4 o_acc[4];
#pragma unroll
        for (int nb = 0; nb < 4; nb++) o_acc[nb] = (f32x4){0.f, 0.f, 0.f, 0.f};
        float m_st[4], l_st[4];
#pragma unroll
        for (int r = 0; r < 4; r++) { m_st[r] = -1e30f; l_st[r] = 0.f; }

        const int qrow_base = q0 + wave * 16 + quad * 4;

        for (int kt = 0; kt < n_iter; kt++) {
            // ---- stage K[128][64] and Vt[64][128] via DMA ----
#pragma unroll
            for (int g = 0; g < 4; g++) {
                gl_lds16(Kbase + (size_t)(kt * 128 + g * 32) * KV_DIM, &Ks[(g * 32 + wave * 8) * 64]);
                gl_lds16(Vbase + (size_t)g * 16 * S_LEN + kt * 128, &Vt[(g * 16 + wave * 4) * 128]);
            }
            __syncthreads();

            // ---- S = Q K^T : 16 MFMAs (8 col-blocks x 2 k-steps) ----
            f32x4 sc[8];
#pragma unroll
            for (int cb = 0; cb < 8; cb++) sc[cb] = (f32x4){0.f, 0.f, 0.f, 0.f};
#pragma unroll
            for (int ks = 0; ks < 2; ks++) {
                const int slot = (ks * 4 + quad) ^ (m16 & 7);
#pragma unroll
                for (int cb = 0; cb < 8; cb++) {
                    bf16x8 kf = *(const bf16x8*)&Ks[(cb * 16 + m16) * 64 + slot * 8];
                    sc[cb] = __builtin_amdgcn_mfma_f32_16x16x32_bf16(qa[ks], kf, sc[cb], 0, 0, 0);
                }
            }

            // ---- scale + causal mask (last tile of this q-tile only) ----
#pragma unroll
            for (int cb = 0; cb < 8; cb++)
#pragma unroll
                for (int r = 0; r < 4; r++) sc[cb][r] *= 0.125f;
            if (kt == n_iter - 1) {
#pragma unroll
                for (int cb = 0; cb < 8; cb++) {
                    int key = kt * 128 + cb * 16 + m16;
#pragma unroll
                    for (int r = 0; r < 4; r++)
                        if (key > qrow_base + r) sc[cb][r] = -1e30f;
                }
            }

            // ---- online softmax ----
            float rmax[4];
#pragma unroll
            for (int r = 0; r < 4; r++) {
                float m01 = fmaxf(fmaxf(sc[0][r], sc[1][r]), fmaxf(sc[2][r], sc[3][r]));
                float m23 = fmaxf(fmaxf(sc[4][r], sc[5][r]), fmaxf(sc[6][r], sc[7][r]));
                rmax[r] = fmaxf(m01, m23);
            }
#pragma unroll
            for (int off = 1; off < 16; off <<= 1)
#pragma unroll
                for (int r = 0; r < 4; r++)
                    rmax[r] = fmaxf(rmax[r], __shfl_xor(rmax[r], off, 64));

            float alpha[4];
#pragma unroll
            for (int r = 0; r < 4; r++) {
                float mnew = fmaxf(m_st[r], rmax[r]);
                alpha[r] = __expf(m_st[r] - mnew);
                m_st[r] = mnew;
            }
            float rsum[4] = {0.f, 0.f, 0.f, 0.f};
#pragma unroll
            for (int cb = 0; cb < 8; cb++)
#pragma unroll
                for (int r = 0; r < 4; r++) {
                    float p = __expf(sc[cb][r] - m_st[r]);
                    sc[cb][r] = p;
                    rsum[r] += p;
                }
#pragma unroll
            for (int off = 1; off < 16; off <<= 1)
#pragma unroll
                for (int r = 0; r < 4; r++)
                    rsum[r] += __shfl_xor(rsum[r], off, 64);
#pragma unroll
            for (int r = 0; r < 4; r++) l_st[r] = l_st[r] * alpha[r] + rsum[r];

            // ---- P (C-layout) -> per-wave LDS [qrow][key] ----
#pragma unroll
            for (int cb = 0; cb < 8; cb++)
#pragma unroll
                for (int r = 0; r < 4; r++)
                    Ps[wave][(quad * 4 + r) * 136 + cb * 16 + m16] = bf16_of(sc[cb][r]);

            // ---- rescale O ----
#pragma unroll
            for (int nb = 0; nb < 4; nb++)
#pragma unroll
                for (int r = 0; r < 4; r++) o_acc[nb][r] *= alpha[r];

            // ---- O += P V : 16 MFMAs (4 k-steps x 4 col-blocks) ----
#pragma unroll
            for (int ks = 0; ks < 4; ks++) {
                bf16x8 pa = *(const bf16x8*)&Ps[wave][m16 * 136 + ks * 32 + quad * 8];
                const int slot = (ks * 4 + quad) ^ (m16 & 7);
#pragma unroll
                for (int nb = 0; nb < 4; nb++) {
                    bf16x8 vf = *(const bf16x8*)&Vt[(nb * 16 + m16) * 128 + slot * 8];
                    o_acc[nb] = __builtin_amdgcn_mfma_f32_16x16x32_bf16(pa, vf, o_acc[nb], 0, 0, 0);
                }
            }
            __syncthreads();
        }

        // ---- epilogue: normalize, store bf16 ----
#pragma unroll
        for (int r = 0; r < 4; r++) {
            float inv_l = 1.f / l_st[r];
#pragma unroll
            for (int nb = 0; nb < 4; nb++)
                out[(size_t)(qrow_base + r) * DIM + h * 64 + nb * 16 + m16] =
                    bf16_of(o_acc[nb][r] * inv_l);
        }
    }
}

// ---------------------------------------------------------------------------
extern "C" void kernel_launch(void* const* d_in, const int* in_sizes, int n_in,
                              void* d_out, int out_size, void* d_ws, size_t ws_size,
                              hipStream_t stream) {
    const float* x    = (const float*)d_in[0];
    const float* wq   = (const float*)d_in[1];
    const float* wk   = (const float*)d_in[2];
    const float* wv   = (const float*)d_in[3];
    const float* wo   = (const float*)d_in[4];
    const float* fcos = (const float*)d_in[5];
    const float* fsin = (const float*)d_in[6];

    char* ws = (char*)d_ws;
    const size_t MB = 1024 * 1024;
    unsigned short* xbf    = (unsigned short*)(ws);            //  8 MB [2048][2048]
    unsigned short* wqkvT  = (unsigned short*)(ws + 8 * MB);   // 12 MB [3072][2048]
    unsigned short* woT    = (unsigned short*)(ws + 20 * MB);  //  8 MB [2048][2048]
    unsigned short* qkvbf  = (unsigned short*)(ws + 28 * MB);  // 12 MB [2048][3072]
    unsigned short* vbt    = (unsigned short*)(ws + 40 * MB);  //  2 MB [512][2048]
    // aliases (producer runs strictly after the aliased buffer is dead):
    unsigned short* qbf    = (unsigned short*)(ws + 8 * MB);   //  8 MB (over wqkvT)
    unsigned short* kbf    = (unsigned short*)(ws + 16 * MB);  //  2 MB (over wqkvT tail)
    unsigned short* attnbf = (unsigned short*)(ws);            //  8 MB (over xbf)

    convert_x<<<(DIM * S_LEN / 4) / 256, 256, 0, stream>>>(x, xbf);
    transpose_cvt<<<dim3(32, 32), 256, 0, stream>>>(wq, wqkvT, DIM, DIM);
    transpose_cvt<<<dim3(8, 32), 256, 0, stream>>>(wk, wqkvT + (size_t)DIM * DIM, KV_DIM, DIM);
    transpose_cvt<<<dim3(8, 32), 256, 0, stream>>>(wv, wqkvT + (size_t)(DIM + KV_DIM) * DIM, KV_DIM, DIM);
    transpose_cvt<<<dim3(32, 32), 256, 0, stream>>>(wo, woT, DIM, DIM);

    gemm_bt<<<dim3(QKV_N / 128, S_LEN / 128), 256, 0, stream>>>(xbf, wqkvT, qkvbf,
                                                                S_LEN, QKV_N, DIM, 1);

    int n_chunks = S_LEN * N_HEADS * 8 + S_LEN * N_KV_HEADS * 8;
    rope_bf16<<<n_chunks / 256, 256, 0, stream>>>(qkvbf, qbf, kbf, fcos, fsin);

    transpose_v_bf16<<<dim3(KV_DIM / 64, S_LEN / 64), 256, 0, stream>>>(qkvbf, vbt);

    attn_mfma2<<<dim3(16, N_HEADS), 256, 0, stream>>>(qbf, kbf, vbt, attnbf);

    gemm_bt<<<dim3(DIM / 128, S_LEN / 128), 256, 0, stream>>>(attnbf, woT, d_out,
                                                              S_LEN, DIM, DIM, 0);
}

// Round 5
// 259.150 us; speedup vs baseline: 7.7456x; 1.0448x over previous
//
#include <hip/hip_runtime.h>
#include <hip/hip_bf16.h>

#define DIM 2048
#define S_LEN 2048
#define N_HEADS 32
#define N_KV_HEADS 8
#define HEAD_DIM 64
#define KV_DIM (N_KV_HEADS * HEAD_DIM)   // 512
#define QKV_N (DIM + 2 * KV_DIM)         // 3072
#define QSCALE 0.18033688011112042f      // 0.125 * log2(e), folded into Q at rope

typedef __attribute__((ext_vector_type(8))) short bf16x8;
typedef __attribute__((ext_vector_type(4))) float f32x4;

__device__ __forceinline__ unsigned short bf16_of(float f) {
    __hip_bfloat16 h = __float2bfloat16(f);
    return *reinterpret_cast<unsigned short*>(&h);
}
__device__ __forceinline__ float f_of_bf16(unsigned short u) {
    unsigned int x = ((unsigned int)u) << 16;
    return __uint_as_float(x);
}
__device__ __forceinline__ void gl_lds16(const void* g, void* l) {
    __builtin_amdgcn_global_load_lds((const __attribute__((address_space(1))) void*)g,
                                     (__attribute__((address_space(3))) void*)l, 16, 0, 0);
}
__device__ __forceinline__ unsigned int pack2bf(float a, float b) {
    return (unsigned int)bf16_of(a) | ((unsigned int)bf16_of(b) << 16);
}

// ---------------------------------------------------------------------------
// x (fp32) -> bf16, straight layout.
// ---------------------------------------------------------------------------
__global__ __launch_bounds__(256) void convert_x(const float* __restrict__ src,
                                                 unsigned short* __restrict__ dst) {
    int idx = blockIdx.x * 256 + threadIdx.x;
    float4 f = ((const float4*)src)[idx];
    ushort4 u;
    u.x = bf16_of(f.x); u.y = bf16_of(f.y); u.z = bf16_of(f.z); u.w = bf16_of(f.w);
    ((ushort4*)dst)[idx] = u;
}

// ---------------------------------------------------------------------------
// Transpose + convert: src fp32 [rows][cols] -> dst bf16 [cols][dst_stride].
// ---------------------------------------------------------------------------
__global__ __launch_bounds__(256) void transpose_cvt(const float* __restrict__ src,
                                                     unsigned short* __restrict__ dst,
                                                     int src_cols, int dst_stride) {
    __shared__ float tile[64][65];
    const int c0 = blockIdx.x * 64;
    const int r0 = blockIdx.y * 64;
    const int t = threadIdx.x;
#pragma unroll
    for (int i = 0; i < 16; i++) {
        int idx = t + i * 256;
        int r = idx >> 6, c = idx & 63;
        tile[r][c] = src[(size_t)(r0 + r) * src_cols + c0 + c];
    }
    __syncthreads();
#pragma unroll
    for (int i = 0; i < 16; i++) {
        int idx = t + i * 256;
        int r = idx >> 6, c = idx & 63;
        dst[(size_t)(c0 + r) * dst_stride + r0 + c] = bf16_of(tile[c][r]);
    }
}

// ---------------------------------------------------------------------------
// bf16 MFMA GEMM (m97-style): C[M][N] = A[M][K] @ Bt[N][K]^T.
// ---------------------------------------------------------------------------
__global__ __launch_bounds__(256) void gemm_bt(const unsigned short* __restrict__ A,
                                               const unsigned short* __restrict__ Bt,
                                               void* __restrict__ Cv,
                                               int M, int N, int K, int c_bf16) {
    __shared__ unsigned short As[128 * 64];
    __shared__ unsigned short Bs[128 * 64];
    const int tid = threadIdx.x;
    const int wave = tid >> 6, lane = tid & 63;
    const int m16 = lane & 15, quad = lane >> 4;
    const int m0 = blockIdx.y * 128, n0 = blockIdx.x * 128;
    const int wm = (wave >> 1) * 64, wn = (wave & 1) * 64;

    const int lrow = lane >> 3;
    const int gc = (lane & 7) ^ lrow;
    const unsigned short* Ab = A + (size_t)(m0 + wave * 8 + lrow) * K + gc * 8;
    const unsigned short* Bb = Bt + (size_t)(n0 + wave * 8 + lrow) * K + gc * 8;

    f32x4 acc[4][4];
#pragma unroll
    for (int mb = 0; mb < 4; mb++)
#pragma unroll
        for (int nb = 0; nb < 4; nb++) acc[mb][nb] = (f32x4){0.f, 0.f, 0.f, 0.f};

    for (int k0 = 0; k0 < K; k0 += 64) {
#pragma unroll
        for (int g = 0; g < 4; g++) {
            gl_lds16(Ab + (size_t)g * 32 * K + k0, &As[(g * 32 + wave * 8) * 64]);
            gl_lds16(Bb + (size_t)g * 32 * K + k0, &Bs[(g * 32 + wave * 8) * 64]);
        }
        __syncthreads();
#pragma unroll
        for (int ks = 0; ks < 2; ks++) {
            bf16x8 af[4], bfr[4];
#pragma unroll
            for (int mb = 0; mb < 4; mb++) {
                int row = wm + mb * 16 + m16;
                int ch = (ks * 4 + quad) ^ (m16 & 7);
                af[mb] = *(const bf16x8*)&As[row * 64 + ch * 8];
                int rowb = wn + mb * 16 + m16;
                bfr[mb] = *(const bf16x8*)&Bs[rowb * 64 + ch * 8];
            }
#pragma unroll
            for (int mb = 0; mb < 4; mb++)
#pragma unroll
                for (int nb = 0; nb < 4; nb++)
                    acc[mb][nb] = __builtin_amdgcn_mfma_f32_16x16x32_bf16(af[mb], bfr[nb], acc[mb][nb], 0, 0, 0);
        }
        __syncthreads();
    }

    if (c_bf16) {
        unsigned short* C = (unsigned short*)Cv;
#pragma unroll
        for (int mb = 0; mb < 4; mb++)
#pragma unroll
            for (int nb = 0; nb < 4; nb++)
#pragma unroll
                for (int r = 0; r < 4; r++)
                    C[(size_t)(m0 + wm + mb * 16 + quad * 4 + r) * N + n0 + wn + nb * 16 + m16] =
                        bf16_of(acc[mb][nb][r]);
    } else {
        float* C = (float*)Cv;
#pragma unroll
        for (int mb = 0; mb < 4; mb++)
#pragma unroll
            for (int nb = 0; nb < 4; nb++)
#pragma unroll
                for (int r = 0; r < 4; r++)
                    C[(size_t)(m0 + wm + mb * 16 + quad * 4 + r) * N + n0 + wn + nb * 16 + m16] =
                        acc[mb][nb][r];
    }
}

// ---------------------------------------------------------------------------
// RoPE: read bf16 qkv [S][3072], rotate in fp32, write bf16 q/k.
// Q is pre-scaled by 0.125*log2(e) so attention scores land in exp2 domain.
// ---------------------------------------------------------------------------
__global__ __launch_bounds__(256) void rope_bf16(const unsigned short* __restrict__ qkv,
                                                 unsigned short* __restrict__ qbf,
                                                 unsigned short* __restrict__ kbf,
                                                 const float* __restrict__ fcos,
                                                 const float* __restrict__ fsin) {
    int idx = blockIdx.x * 256 + threadIdx.x;
    const int nq = S_LEN * N_HEADS * 8;
    int s, j, srcoff, dstoff;
    unsigned short* dst;
    float osc;
    if (idx < nq) {
        s = idx >> 8;
        int rem = idx & 255;
        int h = rem >> 3;
        j = rem & 7;
        srcoff = s * QKV_N + h * 64 + j * 8;
        dstoff = s * DIM + h * 64 + j * 8;
        dst = qbf;
        osc = QSCALE;
    } else {
        int t2 = idx - nq;
        s = t2 >> 6;
        int rem = t2 & 63;
        int h = rem >> 3;
        j = rem & 7;
        srcoff = s * QKV_N + DIM + h * 64 + j * 8;
        dstoff = s * KV_DIM + h * 64 + j * 8;
        dst = kbf;
        osc = 1.0f;
    }
    bf16x8 v8 = *(const bf16x8*)&qkv[srcoff];
    float4 c4 = *(const float4*)&fcos[s * 32 + j * 4];
    float4 s4 = *(const float4*)&fsin[s * 32 + j * 4];
    float cs[4] = {c4.x, c4.y, c4.z, c4.w};
    float sn[4] = {s4.x, s4.y, s4.z, s4.w};
    bf16x8 o;
#pragma unroll
    for (int p = 0; p < 4; p++) {
        float a = f_of_bf16((unsigned short)v8[2 * p]);
        float b = f_of_bf16((unsigned short)v8[2 * p + 1]);
        o[2 * p]     = (short)bf16_of((a * cs[p] - b * sn[p]) * osc);
        o[2 * p + 1] = (short)bf16_of((a * sn[p] + b * cs[p]) * osc);
    }
    *(bf16x8*)&dst[dstoff] = o;
}

// ---------------------------------------------------------------------------
// Transpose V slice of qkv (bf16 [S][3072], cols 2560..3071) -> vbt [512][2048]
// with the key index bit-permuted within each 128-key block:
//   local key bits b6b5(ks) b4(h) b3b2(quad) b1b0(g) -> position ks*32+quad*8+h*4+g.
// This makes the attention PV A-operand (built in-register from S^T fragments)
// line up with contiguous ds_read_b128 of the staged V^T tile.
// ---------------------------------------------------------------------------
__global__ __launch_bounds__(256) void transpose_v_bf16(const unsigned short* __restrict__ qkv,
                                                        unsigned short* __restrict__ vbt) {
    __shared__ unsigned short tile[64][65];
    const int d0 = blockIdx.x * 64;
    const int s0 = blockIdx.y * 64;
    const int t = threadIdx.x;
#pragma unroll
    for (int i = 0; i < 16; i++) {
        int idx = t + i * 256;
        int r = idx >> 6, c = idx & 63;
        tile[r][c] = qkv[(size_t)(s0 + r) * QKV_N + DIM + KV_DIM + d0 + c];
    }
    __syncthreads();
#pragma unroll
    for (int i = 0; i < 16; i++) {
        int idx = t + i * 256;
        int r = idx >> 6, c = idx & 63;
        int key = s0 + c;
        int kl = key & 127;
        int kp = (kl & 0x60) | ((kl & 0x0C) << 1) | ((kl & 0x10) >> 2) | (kl & 3);
        vbt[(size_t)(d0 + r) * S_LEN + (key & ~127) + kp] = tile[c][r];
    }
}

// ---------------------------------------------------------------------------
// Flash attention v3: computes S^T = K @ Q^T per tile (operand-swapped MFMA),
// so each lane's 32 scores belong to ONE Q-row (m16):
//   - softmax reductions: in-lane tree + 2 shuffles (xor 16, 32)
//   - P feeds PV directly from registers (key order permuted to match vbt)
// Block = (head, pair of 64-row Q tiles), 17 x 128-key iterations, uniform.
// ---------------------------------------------------------------------------
__global__ __launch_bounds__(256) void attn_mfma3(const unsigned short* __restrict__ qb,
                                                  const unsigned short* __restrict__ kb,
                                                  const unsigned short* __restrict__ vbt,
                                                  unsigned short* __restrict__ out) {
    const int h  = blockIdx.y;
    const int bx = blockIdx.x;                    // 0..15
    const int kh = h >> 2;
    const int tid  = threadIdx.x;
    const int wave = tid >> 6;
    const int lane = tid & 63;
    const int m16  = lane & 15;
    const int quad = lane >> 4;

    __shared__ unsigned short Ks[128 * 64];       // [key][dim], chunk-swizzled
    __shared__ unsigned short Vt[64 * 128];       // [dim][key(perm)], chunk-swizzled

    const int lrow8 = lane >> 3;
    const int kc    = (lane & 7) ^ lrow8;
    const int lrow4 = lane >> 4;
    const int vc    = (lane & 15) ^ ((wave * 4 + lrow4) & 7);

    const unsigned short* Kbase = kb + (size_t)kh * 64 + (size_t)(wave * 8 + lrow8) * KV_DIM + kc * 8;
    const unsigned short* Vbase = vbt + (size_t)(kh * 64 + wave * 4 + lrow4) * S_LEN + vc * 8;

#pragma unroll
    for (int half = 0; half < 2; half++) {
        const int qt = half ? bx : (31 - bx);
        const int q0 = qt * 64;
        const int n_iter = (qt >> 1) + 1;

        // Q fragment (B-operand layout == A layout): n=qrow=m16, k=dim=quad*8+j
        bf16x8 qa[2];
        {
            const int qrow = q0 + wave * 16 + m16;
#pragma unroll
            for (int ks = 0; ks < 2; ks++)
                qa[ks] = *(const bf16x8*)&qb[(size_t)qrow * DIM + h * 64 + ks * 32 + quad * 8];
        }

        f32x4 o_acc[4];
#pragma unroll
        for (int nb = 0; nb < 4; nb++) o_acc[nb] = (f32x4){0.f, 0.f, 0.f, 0.f};
        float m_s = -1e30f, l_s = 0.f;            // state for row m16
        const int qrow_lane = q0 + wave * 16 + m16;
        const int orow_base = q0 + wave * 16 + quad * 4;

        for (int kt = 0; kt < n_iter; kt++) {
            // ---- stage K[128][64] and Vt[64][128] via DMA ----
#pragma unroll
            for (int g = 0; g < 4; g++) {
                gl_lds16(Kbase + (size_t)(kt * 128 + g * 32) * KV_DIM, &Ks[(g * 32 + wave * 8) * 64]);
                gl_lds16(Vbase + (size_t)g * 16 * S_LEN + kt * 128, &Vt[(g * 16 + wave * 4) * 128]);
            }
            __syncthreads();

            // ---- S^T = K Q^T : sc[cb] holds keys cb*16+quad*4+r, qrow m16 ----
            f32x4 sc[8];
#pragma unroll
            for (int cb = 0; cb < 8; cb++) sc[cb] = (f32x4){0.f, 0.f, 0.f, 0.f};
#pragma unroll
            for (int ks = 0; ks < 2; ks++) {
                const int slot = (ks * 4 + quad) ^ (m16 & 7);
#pragma unroll
                for (int cb = 0; cb < 8; cb++) {
                    bf16x8 kf = *(const bf16x8*)&Ks[(cb * 16 + m16) * 64 + slot * 8];
                    sc[cb] = __builtin_amdgcn_mfma_f32_16x16x32_bf16(kf, qa[ks], sc[cb], 0, 0, 0);
                }
            }

            // ---- causal mask (last tile of this q-tile only) ----
            if (kt == n_iter - 1) {
#pragma unroll
                for (int cb = 0; cb < 8; cb++) {
                    int key = kt * 128 + cb * 16 + quad * 4;
#pragma unroll
                    for (int r = 0; r < 4; r++)
                        if (key + r > qrow_lane) sc[cb][r] = -1e30f;
                }
            }

            // ---- online softmax (exp2 domain; all 32 values are row m16) ----
            float rmax = sc[0][0];
#pragma unroll
            for (int cb = 0; cb < 8; cb++)
#pragma unroll
                for (int r = 0; r < 4; r++) rmax = fmaxf(rmax, sc[cb][r]);
            rmax = fmaxf(rmax, __shfl_xor(rmax, 16, 64));
            rmax = fmaxf(rmax, __shfl_xor(rmax, 32, 64));

            float mnew = fmaxf(m_s, rmax);
            float alpha = __builtin_amdgcn_exp2f(m_s - mnew);
            m_s = mnew;

            float rsum = 0.f;
#pragma unroll
            for (int cb = 0; cb < 8; cb++)
#pragma unroll
                for (int r = 0; r < 4; r++) {
                    float p = __builtin_amdgcn_exp2f(sc[cb][r] - mnew);
                    sc[cb][r] = p;
                    rsum += p;
                }
            rsum += __shfl_xor(rsum, 16, 64);
            rsum += __shfl_xor(rsum, 32, 64);
            l_s = l_s * alpha + rsum;

            // ---- pack P fragments (in-register; key order matches vbt perm) ----
            unsigned int P01[8], P23[8];
#pragma unroll
            for (int cb = 0; cb < 8; cb++) {
                P01[cb] = pack2bf(sc[cb][0], sc[cb][1]);
                P23[cb] = pack2bf(sc[cb][2], sc[cb][3]);
            }

            // ---- rescale O by alpha of row quad*4+r ----
#pragma unroll
            for (int r = 0; r < 4; r++) {
                float a_r = __shfl(alpha, quad * 4 + r, 64);
#pragma unroll
                for (int nb = 0; nb < 4; nb++) o_acc[nb][r] *= a_r;
            }

            // ---- O += P V : A-frag from own registers, B-frag from Vt ----
#pragma unroll
            for (int ks = 0; ks < 4; ks++) {
                union { unsigned int u[4]; bf16x8 v; } pa;
                pa.u[0] = P01[2 * ks];     pa.u[1] = P23[2 * ks];
                pa.u[2] = P01[2 * ks + 1]; pa.u[3] = P23[2 * ks + 1];
                const int slot = (ks * 4 + quad) ^ (m16 & 7);
#pragma unroll
                for (int nb = 0; nb < 4; nb++) {
                    bf16x8 vf = *(const bf16x8*)&Vt[(nb * 16 + m16) * 128 + slot * 8];
                    o_acc[nb] = __builtin_amdgcn_mfma_f32_16x16x32_bf16(pa.v, vf, o_acc[nb], 0, 0, 0);
                }
            }
            __syncthreads();
        }

        // ---- epilogue: normalize by l of row quad*4+r, store bf16 ----
#pragma unroll
        for (int r = 0; r < 4; r++) {
            float l_r = __shfl(l_s, quad * 4 + r, 64);
            float inv_l = 1.f / l_r;
#pragma unroll
            for (int nb = 0; nb < 4; nb++)
                out[(size_t)(orow_base + r) * DIM + h * 64 + nb * 16 + m16] =
                    bf16_of(o_acc[nb][r] * inv_l);
        }
    }
}

// ---------------------------------------------------------------------------
extern "C" void kernel_launch(void* const* d_in, const int* in_sizes, int n_in,
                              void* d_out, int out_size, void* d_ws, size_t ws_size,
                              hipStream_t stream) {
    const float* x    = (const float*)d_in[0];
    const float* wq   = (const float*)d_in[1];
    const float* wk   = (const float*)d_in[2];
    const float* wv   = (const float*)d_in[3];
    const float* wo   = (const float*)d_in[4];
    const float* fcos = (const float*)d_in[5];
    const float* fsin = (const float*)d_in[6];

    char* ws = (char*)d_ws;
    const size_t MB = 1024 * 1024;
    unsigned short* xbf    = (unsigned short*)(ws);            //  8 MB [2048][2048]
    unsigned short* wqkvT  = (unsigned short*)(ws + 8 * MB);   // 12 MB [3072][2048]
    unsigned short* woT    = (unsigned short*)(ws + 20 * MB);  //  8 MB [2048][2048]
    unsigned short* qkvbf  = (unsigned short*)(ws + 28 * MB);  // 12 MB [2048][3072]
    unsigned short* vbt    = (unsigned short*)(ws + 40 * MB);  //  2 MB [512][2048]
    unsigned short* qbf    = (unsigned short*)(ws + 8 * MB);   //  8 MB (over wqkvT)
    unsigned short* kbf    = (unsigned short*)(ws + 16 * MB);  //  2 MB (over wqkvT tail)
    unsigned short* attnbf = (unsigned short*)(ws);            //  8 MB (over xbf)

    convert_x<<<(DIM * S_LEN / 4) / 256, 256, 0, stream>>>(x, xbf);
    transpose_cvt<<<dim3(32, 32), 256, 0, stream>>>(wq, wqkvT, DIM, DIM);
    transpose_cvt<<<dim3(8, 32), 256, 0, stream>>>(wk, wqkvT + (size_t)DIM * DIM, KV_DIM, DIM);
    transpose_cvt<<<dim3(8, 32), 256, 0, stream>>>(wv, wqkvT + (size_t)(DIM + KV_DIM) * DIM, KV_DIM, DIM);
    transpose_cvt<<<dim3(32, 32), 256, 0, stream>>>(wo, woT, DIM, DIM);

    gemm_bt<<<dim3(QKV_N / 128, S_LEN / 128), 256, 0, stream>>>(xbf, wqkvT, qkvbf,
                                                                S_LEN, QKV_N, DIM, 1);

    int n_chunks = S_LEN * N_HEADS * 8 + S_LEN * N_KV_HEADS * 8;
    rope_bf16<<<n_chunks / 256, 256, 0, stream>>>(qkvbf, qbf, kbf, fcos, fsin);

    transpose_v_bf16<<<dim3(KV_DIM / 64, S_LEN / 64), 256, 0, stream>>>(qkvbf, vbt);

    attn_mfma3<<<dim3(16, N_HEADS), 256, 0, stream>>>(qbf, kbf, vbt, attnbf);

    gemm_bt<<<dim3(DIM / 128, S_LEN / 128), 256, 0, stream>>>(attnbf, woT, d_out,
                                                              S_LEN, DIM, DIM, 0);
}

// Round 6
// 238.729 us; speedup vs baseline: 8.4081x; 1.0855x over previous
//
#include <hip/hip_runtime.h>
#include <hip/hip_bf16.h>

#define DIM 2048
#define S_LEN 2048
#define N_HEADS 32
#define N_KV_HEADS 8
#define HEAD_DIM 64
#define KV_DIM (N_KV_HEADS * HEAD_DIM)   // 512
#define QKV_N (DIM + 2 * KV_DIM)         // 3072
#define QSCALE 0.18033688011112042f      // 0.125 * log2(e), folded into Q at rope

typedef __attribute__((ext_vector_type(8))) short bf16x8;
typedef __attribute__((ext_vector_type(4))) float f32x4;

__device__ __forceinline__ unsigned short bf16_of(float f) {
    __hip_bfloat16 h = __float2bfloat16(f);
    return *reinterpret_cast<unsigned short*>(&h);
}
__device__ __forceinline__ float f_of_bf16(unsigned short u) {
    unsigned int x = ((unsigned int)u) << 16;
    return __uint_as_float(x);
}
__device__ __forceinline__ void gl_lds16(const void* g, void* l) {
    __builtin_amdgcn_global_load_lds((const __attribute__((address_space(1))) void*)g,
                                     (__attribute__((address_space(3))) void*)l, 16, 0, 0);
}
__device__ __forceinline__ unsigned int pack2bf(float a, float b) {
    return (unsigned int)bf16_of(a) | ((unsigned int)bf16_of(b) << 16);
}

// ---------------------------------------------------------------------------
// prep: fused x->bf16 convert (blocks 0..4095) + 4 weight transpose/converts
// (blocks 4096..6655).  All weight transposes land in [N][K=2048] bf16.
// ---------------------------------------------------------------------------
__global__ __launch_bounds__(256) void prep(const float* __restrict__ x,
                                            const float* __restrict__ wq,
                                            const float* __restrict__ wk,
                                            const float* __restrict__ wv,
                                            const float* __restrict__ wo,
                                            unsigned short* __restrict__ xbf,
                                            unsigned short* __restrict__ wqkvT,
                                            unsigned short* __restrict__ woT) {
    __shared__ float tile[64][65];
    const int t = threadIdx.x;
    int b = blockIdx.x;
    if (b < 4096) {
        int idx = b * 256 + t;
        float4 f = ((const float4*)x)[idx];
        ushort4 u;
        u.x = bf16_of(f.x); u.y = bf16_of(f.y); u.z = bf16_of(f.z); u.w = bf16_of(f.w);
        ((ushort4*)xbf)[idx] = u;
        return;
    }
    b -= 4096;
    const float* src;
    unsigned short* dst;
    int src_cols, bx, by;
    if (b < 1024)      { src = wq; dst = wqkvT;                                src_cols = DIM;    bx = b & 31;          by = b >> 5; }
    else if (b < 1280) { src = wk; dst = wqkvT + (size_t)DIM * DIM;            src_cols = KV_DIM; bx = (b - 1024) & 7;  by = (b - 1024) >> 3; }
    else if (b < 1536) { src = wv; dst = wqkvT + (size_t)(DIM + KV_DIM) * DIM; src_cols = KV_DIM; bx = (b - 1280) & 7;  by = (b - 1280) >> 3; }
    else               { src = wo; dst = woT;                                  src_cols = DIM;    bx = (b - 1536) & 31; by = (b - 1536) >> 5; }
    const int c0 = bx * 64, r0 = by * 64;
#pragma unroll
    for (int i = 0; i < 16; i++) {
        int idx = t + i * 256;
        int r = idx >> 6, c = idx & 63;
        tile[r][c] = src[(size_t)(r0 + r) * src_cols + c0 + c];
    }
    __syncthreads();
#pragma unroll
    for (int i = 0; i < 16; i++) {
        int idx = t + i * 256;
        int r = idx >> 6, c = idx & 63;
        dst[(size_t)(c0 + r) * DIM + r0 + c] = bf16_of(tile[c][r]);
    }
}

// ---------------------------------------------------------------------------
// bf16 MFMA GEMM, 128(M) x 64(N) tile, BK=64, 4 waves (2x2, each 64x32).
// C[M][N] = A[M][K] @ Bt[N][K]^T.  More blocks than the 128x128 variant ->
// 2-3 blocks/CU at these shapes (barrier drains hidden by co-resident blocks).
// ---------------------------------------------------------------------------
__global__ __launch_bounds__(256) void gemm_bt64(const unsigned short* __restrict__ A,
                                                 const unsigned short* __restrict__ Bt,
                                                 void* __restrict__ Cv,
                                                 int M, int N, int K, int c_bf16) {
    __shared__ unsigned short As[128 * 64];
    __shared__ unsigned short Bs[64 * 64];
    const int tid = threadIdx.x;
    const int wave = tid >> 6, lane = tid & 63;
    const int m16 = lane & 15, quad = lane >> 4;
    const int m0 = blockIdx.y * 128, n0 = blockIdx.x * 64;
    const int wm = (wave >> 1) * 64, wn = (wave & 1) * 32;

    const int lrow = lane >> 3;
    const int gc = (lane & 7) ^ lrow;
    const unsigned short* Ab = A + (size_t)(m0 + wave * 8 + lrow) * K + gc * 8;
    const unsigned short* Bb = Bt + (size_t)(n0 + wave * 8 + lrow) * K + gc * 8;

    f32x4 acc[4][2];
#pragma unroll
    for (int mb = 0; mb < 4; mb++)
#pragma unroll
        for (int nb = 0; nb < 2; nb++) acc[mb][nb] = (f32x4){0.f, 0.f, 0.f, 0.f};

    for (int k0 = 0; k0 < K; k0 += 64) {
#pragma unroll
        for (int g = 0; g < 4; g++)
            gl_lds16(Ab + (size_t)g * 32 * K + k0, &As[(g * 32 + wave * 8) * 64]);
#pragma unroll
        for (int g = 0; g < 2; g++)
            gl_lds16(Bb + (size_t)g * 32 * K + k0, &Bs[(g * 32 + wave * 8) * 64]);
        __syncthreads();
#pragma unroll
        for (int ks = 0; ks < 2; ks++) {
            const int ch = (ks * 4 + quad) ^ (m16 & 7);
            bf16x8 af[4], bfr[2];
#pragma unroll
            for (int mb = 0; mb < 4; mb++)
                af[mb] = *(const bf16x8*)&As[(wm + mb * 16 + m16) * 64 + ch * 8];
#pragma unroll
            for (int nb = 0; nb < 2; nb++)
                bfr[nb] = *(const bf16x8*)&Bs[(wn + nb * 16 + m16) * 64 + ch * 8];
#pragma unroll
            for (int mb = 0; mb < 4; mb++)
#pragma unroll
                for (int nb = 0; nb < 2; nb++)
                    acc[mb][nb] = __builtin_amdgcn_mfma_f32_16x16x32_bf16(af[mb], bfr[nb], acc[mb][nb], 0, 0, 0);
        }
        __syncthreads();
    }

    if (c_bf16) {
        unsigned short* C = (unsigned short*)Cv;
#pragma unroll
        for (int mb = 0; mb < 4; mb++)
#pragma unroll
            for (int nb = 0; nb < 2; nb++)
#pragma unroll
                for (int r = 0; r < 4; r++)
                    C[(size_t)(m0 + wm + mb * 16 + quad * 4 + r) * N + n0 + wn + nb * 16 + m16] =
                        bf16_of(acc[mb][nb][r]);
    } else {
        float* C = (float*)Cv;
#pragma unroll
        for (int mb = 0; mb < 4; mb++)
#pragma unroll
            for (int nb = 0; nb < 2; nb++)
#pragma unroll
                for (int r = 0; r < 4; r++)
                    C[(size_t)(m0 + wm + mb * 16 + quad * 4 + r) * N + n0 + wn + nb * 16 + m16] =
                        acc[mb][nb][r];
    }
}

// ---------------------------------------------------------------------------
// rope_tv: fused RoPE (blocks 0..2559) + V transpose-with-key-permute
// (blocks 2560..2815).  RoPE pre-scales Q by 0.125*log2(e) (exp2 domain).
// V perm within each 128-key block: b6b5 b4 b3b2 b1b0 -> ks*32+quad*8+h*4+g,
// matching the attention PV in-register A-fragment order.
// ---------------------------------------------------------------------------
__global__ __launch_bounds__(256) void rope_tv(const unsigned short* __restrict__ qkv,
                                               unsigned short* __restrict__ qbf,
                                               unsigned short* __restrict__ kbf,
                                               unsigned short* __restrict__ vbt,
                                               const float* __restrict__ fcos,
                                               const float* __restrict__ fsin) {
    __shared__ unsigned short tile[64][65];
    const int t = threadIdx.x;
    int b = blockIdx.x;
    if (b < 2560) {
        int idx = b * 256 + t;
        const int nq = S_LEN * N_HEADS * 8;
        int s, j, srcoff, dstoff;
        unsigned short* dst;
        float osc;
        if (idx < nq) {
            s = idx >> 8;
            int rem = idx & 255;
            int h = rem >> 3;
            j = rem & 7;
            srcoff = s * QKV_N + h * 64 + j * 8;
            dstoff = s * DIM + h * 64 + j * 8;
            dst = qbf;
            osc = QSCALE;
        } else {
            int t2 = idx - nq;
            s = t2 >> 6;
            int rem = t2 & 63;
            int h = rem >> 3;
            j = rem & 7;
            srcoff = s * QKV_N + DIM + h * 64 + j * 8;
            dstoff = s * KV_DIM + h * 64 + j * 8;
            dst = kbf;
            osc = 1.0f;
        }
        bf16x8 v8 = *(const bf16x8*)&qkv[srcoff];
        float4 c4 = *(const float4*)&fcos[s * 32 + j * 4];
        float4 s4 = *(const float4*)&fsin[s * 32 + j * 4];
        float cs[4] = {c4.x, c4.y, c4.z, c4.w};
        float sn[4] = {s4.x, s4.y, s4.z, s4.w};
        bf16x8 o;
#pragma unroll
        for (int p = 0; p < 4; p++) {
            float a = f_of_bf16((unsigned short)v8[2 * p]);
            float bb = f_of_bf16((unsigned short)v8[2 * p + 1]);
            o[2 * p]     = (short)bf16_of((a * cs[p] - bb * sn[p]) * osc);
            o[2 * p + 1] = (short)bf16_of((a * sn[p] + bb * cs[p]) * osc);
        }
        *(bf16x8*)&dst[dstoff] = o;
        return;
    }
    b -= 2560;                                    // 0..255  (8 x 32)
    const int d0 = (b & 7) * 64;
    const int s0 = (b >> 3) * 64;
#pragma unroll
    for (int i = 0; i < 16; i++) {
        int idx = t + i * 256;
        int r = idx >> 6, c = idx & 63;
        tile[r][c] = qkv[(size_t)(s0 + r) * QKV_N + DIM + KV_DIM + d0 + c];
    }
    __syncthreads();
#pragma unroll
    for (int i = 0; i < 16; i++) {
        int idx = t + i * 256;
        int r = idx >> 6, c = idx & 63;
        int key = s0 + c;
        int kl = key & 127;
        int kp = (kl & 0x60) | ((kl & 0x0C) << 1) | ((kl & 0x10) >> 2) | (kl & 3);
        vbt[(size_t)(d0 + r) * S_LEN + (key & ~127) + kp] = tile[c][r];
    }
}

// ---------------------------------------------------------------------------
// Flash attention v4: split-K flash.  blockIdx = (bx 0..15, part 0..1, head).
// Block handles the `part` half of the key-range for q-tile pair
// (qt=31-bx, qt=bx).  Partials: normalized O (bf16) + (m,l) f32 per row.
// S^T trick (operand-swapped MFMA), in-register P, exp2-domain softmax.
// ---------------------------------------------------------------------------
__global__ __launch_bounds__(256) void attn_mfma4(const unsigned short* __restrict__ qb,
                                                  const unsigned short* __restrict__ kb,
                                                  const unsigned short* __restrict__ vbt,
                                                  unsigned short* __restrict__ O0,
                                                  unsigned short* __restrict__ O1,
                                                  float2* __restrict__ ml0,
                                                  float2* __restrict__ ml1) {
    const int bx   = blockIdx.x;                  // 0..15
    const int part = blockIdx.y;                  // 0..1
    const int h    = blockIdx.z;                  // 0..31
    const int kh = h >> 2;
    const int tid  = threadIdx.x;
    const int wave = tid >> 6;
    const int lane = tid & 63;
    const int m16  = lane & 15;
    const int quad = lane >> 4;

    unsigned short* Op = part ? O1 : O0;
    float2* mlp = part ? ml1 : ml0;

    __shared__ unsigned short Ks[128 * 64];       // [key][dim], chunk-swizzled
    __shared__ unsigned short Vt[64 * 128];       // [dim][key(perm)], chunk-swizzled

    const int lrow8 = lane >> 3;
    const int kc    = (lane & 7) ^ lrow8;
    const int lrow4 = lane >> 4;
    const int vc    = (lane & 15) ^ ((wave * 4 + lrow4) & 7);

    const unsigned short* Kbase = kb + (size_t)kh * 64 + (size_t)(wave * 8 + lrow8) * KV_DIM + kc * 8;
    const unsigned short* Vbase = vbt + (size_t)(kh * 64 + wave * 4 + lrow4) * S_LEN + vc * 8;

#pragma unroll
    for (int half = 0; half < 2; half++) {
        const int qt = half ? bx : (31 - bx);
        const int q0 = qt * 64;
        const int n_full = (qt >> 1) + 1;
        const int n0 = (n_full + 1) >> 1;
        const int kt_lo = part ? n0 : 0;
        const int kt_hi = part ? n_full : n0;

        bf16x8 qa[2];
        {
            const int qrow = q0 + wave * 16 + m16;
#pragma unroll
            for (int ks = 0; ks < 2; ks++)
                qa[ks] = *(const bf16x8*)&qb[(size_t)qrow * DIM + h * 64 + ks * 32 + quad * 8];
        }

        f32x4 o_acc[4];
#pragma unroll
        for (int nb = 0; nb < 4; nb++) o_acc[nb] = (f32x4){0.f, 0.f, 0.f, 0.f};
        float m_s = -1e30f, l_s = 0.f;
        const int qrow_lane = q0 + wave * 16 + m16;
        const int orow_base = q0 + wave * 16 + quad * 4;

        for (int kt = kt_lo; kt < kt_hi; kt++) {
#pragma unroll
            for (int g = 0; g < 4; g++) {
                gl_lds16(Kbase + (size_t)(kt * 128 + g * 32) * KV_DIM, &Ks[(g * 32 + wave * 8) * 64]);
                gl_lds16(Vbase + (size_t)g * 16 * S_LEN + kt * 128, &Vt[(g * 16 + wave * 4) * 128]);
            }
            __syncthreads();

            f32x4 sc[8];
#pragma unroll
            for (int cb = 0; cb < 8; cb++) sc[cb] = (f32x4){0.f, 0.f, 0.f, 0.f};
#pragma unroll
            for (int ks = 0; ks < 2; ks++) {
                const int slot = (ks * 4 + quad) ^ (m16 & 7);
#pragma unroll
                for (int cb = 0; cb < 8; cb++) {
                    bf16x8 kf = *(const bf16x8*)&Ks[(cb * 16 + m16) * 64 + slot * 8];
                    sc[cb] = __builtin_amdgcn_mfma_f32_16x16x32_bf16(kf, qa[ks], sc[cb], 0, 0, 0);
                }
            }

            if (kt == n_full - 1) {
#pragma unroll
                for (int cb = 0; cb < 8; cb++) {
                    int key = kt * 128 + cb * 16 + quad * 4;
#pragma unroll
                    for (int r = 0; r < 4; r++)
                        if (key + r > qrow_lane) sc[cb][r] = -1e30f;
                }
            }

            float rmax = sc[0][0];
#pragma unroll
            for (int cb = 0; cb < 8; cb++)
#pragma unroll
                for (int r = 0; r < 4; r++) rmax = fmaxf(rmax, sc[cb][r]);
            rmax = fmaxf(rmax, __shfl_xor(rmax, 16, 64));
            rmax = fmaxf(rmax, __shfl_xor(rmax, 32, 64));

            float mnew = fmaxf(m_s, rmax);
            float alpha = __builtin_amdgcn_exp2f(m_s - mnew);
            m_s = mnew;

            float rsum = 0.f;
#pragma unroll
            for (int cb = 0; cb < 8; cb++)
#pragma unroll
                for (int r = 0; r < 4; r++) {
                    float p = __builtin_amdgcn_exp2f(sc[cb][r] - mnew);
                    sc[cb][r] = p;
                    rsum += p;
                }
            rsum += __shfl_xor(rsum, 16, 64);
            rsum += __shfl_xor(rsum, 32, 64);
            l_s = l_s * alpha + rsum;

            unsigned int P01[8], P23[8];
#pragma unroll
            for (int cb = 0; cb < 8; cb++) {
                P01[cb] = pack2bf(sc[cb][0], sc[cb][1]);
                P23[cb] = pack2bf(sc[cb][2], sc[cb][3]);
            }

#pragma unroll
            for (int r = 0; r < 4; r++) {
                float a_r = __shfl(alpha, quad * 4 + r, 64);
#pragma unroll
                for (int nb = 0; nb < 4; nb++) o_acc[nb][r] *= a_r;
            }

#pragma unroll
            for (int ks = 0; ks < 4; ks++) {
                union { unsigned int u[4]; bf16x8 v; } pa;
                pa.u[0] = P01[2 * ks];     pa.u[1] = P23[2 * ks];
                pa.u[2] = P01[2 * ks + 1]; pa.u[3] = P23[2 * ks + 1];
                const int slot = (ks * 4 + quad) ^ (m16 & 7);
#pragma unroll
                for (int nb = 0; nb < 4; nb++) {
                    bf16x8 vf = *(const bf16x8*)&Vt[(nb * 16 + m16) * 128 + slot * 8];
                    o_acc[nb] = __builtin_amdgcn_mfma_f32_16x16x32_bf16(pa.v, vf, o_acc[nb], 0, 0, 0);
                }
            }
            __syncthreads();
        }

        // ---- epilogue: write normalized partial O + (m,l) ----
#pragma unroll
        for (int r = 0; r < 4; r++) {
            float l_r = __shfl(l_s, quad * 4 + r, 64);
            float inv_l = (l_r > 0.f) ? (1.f / l_r) : 0.f;
#pragma unroll
            for (int nb = 0; nb < 4; nb++)
                Op[(size_t)(orow_base + r) * DIM + h * 64 + nb * 16 + m16] =
                    bf16_of(o_acc[nb][r] * inv_l);
        }
        if (quad == 0)
            mlp[h * S_LEN + q0 + wave * 16 + m16] = make_float2(m_s, l_s);
    }
}

// ---------------------------------------------------------------------------
// combine: attn = (w0*O0 + w1*O1) / (w0+w1), w_i = l_i * 2^(m_i - m).
// In-place into O0 (= attnbf).  One thread = 4 cols (same head).
// ---------------------------------------------------------------------------
__global__ __launch_bounds__(256) void combine(unsigned short* __restrict__ O0,
                                               const unsigned short* __restrict__ O1,
                                               const float2* __restrict__ ml0,
                                               const float2* __restrict__ ml1) {
    int idx = blockIdx.x * 256 + threadIdx.x;     // over S*DIM/4
    int row = idx >> 9;
    int cc = (idx & 511) * 4;
    int h = cc >> 6;
    float2 a0 = ml0[h * S_LEN + row];
    float2 a1 = ml1[h * S_LEN + row];
    float m = fmaxf(a0.x, a1.x);
    float w0 = a0.y * __builtin_amdgcn_exp2f(a0.x - m);
    float w1 = a1.y * __builtin_amdgcn_exp2f(a1.x - m);
    float inv = 1.f / (w0 + w1);
    w0 *= inv; w1 *= inv;
    ushort4 u0 = *(const ushort4*)&O0[(size_t)row * DIM + cc];
    ushort4 u1 = *(const ushort4*)&O1[(size_t)row * DIM + cc];
    ushort4 o;
    o.x = bf16_of(w0 * f_of_bf16(u0.x) + w1 * f_of_bf16(u1.x));
    o.y = bf16_of(w0 * f_of_bf16(u0.y) + w1 * f_of_bf16(u1.y));
    o.z = bf16_of(w0 * f_of_bf16(u0.z) + w1 * f_of_bf16(u1.z));
    o.w = bf16_of(w0 * f_of_bf16(u0.w) + w1 * f_of_bf16(u1.w));
    *(ushort4*)&O0[(size_t)row * DIM + cc] = o;
}

// ---------------------------------------------------------------------------
extern "C" void kernel_launch(void* const* d_in, const int* in_sizes, int n_in,
                              void* d_out, int out_size, void* d_ws, size_t ws_size,
                              hipStream_t stream) {
    const float* x    = (const float*)d_in[0];
    const float* wq   = (const float*)d_in[1];
    const float* wk   = (const float*)d_in[2];
    const float* wv   = (const float*)d_in[3];
    const float* wo   = (const float*)d_in[4];
    const float* fcos = (const float*)d_in[5];
    const float* fsin = (const float*)d_in[6];

    char* ws = (char*)d_ws;
    const size_t MB = 1024 * 1024;
    unsigned short* xbf    = (unsigned short*)(ws);             //  8 MB [2048][2048]
    unsigned short* wqkvT  = (unsigned short*)(ws + 8 * MB);    // 12 MB [3072][2048]
    unsigned short* woT    = (unsigned short*)(ws + 20 * MB);   //  8 MB [2048][2048]
    unsigned short* qkvbf  = (unsigned short*)(ws + 28 * MB);   // 12 MB [2048][3072]
    unsigned short* vbt    = (unsigned short*)(ws + 40 * MB);   //  2 MB [512][2048]
    float2*         ml0    = (float2*)(ws + 42 * MB);           // 0.5 MB [32][2048]
    float2*         ml1    = (float2*)(ws + 42 * MB + 512 * 1024);
    // aliases (producer runs strictly after aliased buffer is dead):
    unsigned short* qbf    = (unsigned short*)(ws + 8 * MB);    //  8 MB (over wqkvT)
    unsigned short* kbf    = (unsigned short*)(ws + 16 * MB);   //  2 MB (over wqkvT tail)
    unsigned short* Opart0 = (unsigned short*)(ws);             //  8 MB (over xbf) = attnbf
    unsigned short* Opart1 = (unsigned short*)(ws + 28 * MB);   //  8 MB (over qkvbf)

    // 1. convert x + transpose weights (fused)
    prep<<<4096 + 2560, 256, 0, stream>>>(x, wq, wk, wv, wo, xbf, wqkvT, woT);

    // 2. fused QKV projection (bf16 out)
    gemm_bt64<<<dim3(QKV_N / 64, S_LEN / 128), 256, 0, stream>>>(xbf, wqkvT, qkvbf,
                                                                 S_LEN, QKV_N, DIM, 1);

    // 3. RoPE + V transpose (fused)
    rope_tv<<<2560 + 256, 256, 0, stream>>>(qkvbf, qbf, kbf, vbt, fcos, fsin);

    // 4. split-K flash attention
    attn_mfma4<<<dim3(16, 2, N_HEADS), 256, 0, stream>>>(qbf, kbf, vbt,
                                                         Opart0, Opart1, ml0, ml1);

    // 5. combine partials -> attnbf (= Opart0, in place)
    combine<<<(S_LEN * DIM / 4) / 256, 256, 0, stream>>>(Opart0, Opart1, ml0, ml1);

    // 6. output projection (fp32 out)
    gemm_bt64<<<dim3(DIM / 64, S_LEN / 128), 256, 0, stream>>>(Opart0, woT, d_out,
                                                               S_LEN, DIM, DIM, 0);
}

// Round 7
// 227.687 us; speedup vs baseline: 8.8159x; 1.0485x over previous
//
#include <hip/hip_runtime.h>
#include <hip/hip_bf16.h>

#define DIM 2048
#define S_LEN 2048
#define N_HEADS 32
#define N_KV_HEADS 8
#define HEAD_DIM 64
#define KV_DIM (N_KV_HEADS * HEAD_DIM)   // 512
#define QKV_N (DIM + 2 * KV_DIM)         // 3072
#define QSCALE 0.18033688011112042f      // 0.125 * log2(e), folded into Q at rope

typedef __attribute__((ext_vector_type(8))) short bf16x8;
typedef __attribute__((ext_vector_type(4))) float f32x4;

__device__ __forceinline__ unsigned short bf16_of(float f) {
    __hip_bfloat16 h = __float2bfloat16(f);
    return *reinterpret_cast<unsigned short*>(&h);
}
__device__ __forceinline__ float f_of_bf16(unsigned short u) {
    unsigned int x = ((unsigned int)u) << 16;
    return __uint_as_float(x);
}
__device__ __forceinline__ void gl_lds16(const void* g, void* l) {
    __builtin_amdgcn_global_load_lds((const __attribute__((address_space(1))) void*)g,
                                     (__attribute__((address_space(3))) void*)l, 16, 0, 0);
}
// pack two fp32 -> bf16x2 by truncation: one v_perm_b32
__device__ __forceinline__ unsigned int pack2tr(float lo, float hi) {
    return __builtin_amdgcn_perm(__float_as_uint(hi), __float_as_uint(lo), 0x07060302u);
}

// ---------------------------------------------------------------------------
// prep: fused x->bf16 convert (blocks 0..4095) + 4 weight transpose/converts
// (blocks 4096..6655).  All weight transposes land in [N][K=2048] bf16.
// ---------------------------------------------------------------------------
__global__ __launch_bounds__(256) void prep(const float* __restrict__ x,
                                            const float* __restrict__ wq,
                                            const float* __restrict__ wk,
                                            const float* __restrict__ wv,
                                            const float* __restrict__ wo,
                                            unsigned short* __restrict__ xbf,
                                            unsigned short* __restrict__ wqkvT,
                                            unsigned short* __restrict__ woT) {
    __shared__ float tile[64][65];
    const int t = threadIdx.x;
    int b = blockIdx.x;
    if (b < 4096) {
        int idx = b * 256 + t;
        float4 f = ((const float4*)x)[idx];
        ushort4 u;
        u.x = bf16_of(f.x); u.y = bf16_of(f.y); u.z = bf16_of(f.z); u.w = bf16_of(f.w);
        ((ushort4*)xbf)[idx] = u;
        return;
    }
    b -= 4096;
    const float* src;
    unsigned short* dst;
    int src_cols, bx, by;
    if (b < 1024)      { src = wq; dst = wqkvT;                                src_cols = DIM;    bx = b & 31;          by = b >> 5; }
    else if (b < 1280) { src = wk; dst = wqkvT + (size_t)DIM * DIM;            src_cols = KV_DIM; bx = (b - 1024) & 7;  by = (b - 1024) >> 3; }
    else if (b < 1536) { src = wv; dst = wqkvT + (size_t)(DIM + KV_DIM) * DIM; src_cols = KV_DIM; bx = (b - 1280) & 7;  by = (b - 1280) >> 3; }
    else               { src = wo; dst = woT;                                  src_cols = DIM;    bx = (b - 1536) & 31; by = (b - 1536) >> 5; }
    const int c0 = bx * 64, r0 = by * 64;
#pragma unroll
    for (int i = 0; i < 16; i++) {
        int idx = t + i * 256;
        int r = idx >> 6, c = idx & 63;
        tile[r][c] = src[(size_t)(r0 + r) * src_cols + c0 + c];
    }
    __syncthreads();
#pragma unroll
    for (int i = 0; i < 16; i++) {
        int idx = t + i * 256;
        int r = idx >> 6, c = idx & 63;
        dst[(size_t)(c0 + r) * DIM + r0 + c] = bf16_of(tile[c][r]);
    }
}

// ---------------------------------------------------------------------------
// bf16 MFMA GEMM, 128(M) x 64(N) tile, BK=64, 4 waves (2x2, each 64x32).
// C[M][N] = A[M][K] @ Bt[N][K]^T.
// ---------------------------------------------------------------------------
__global__ __launch_bounds__(256) void gemm_bt64(const unsigned short* __restrict__ A,
                                                 const unsigned short* __restrict__ Bt,
                                                 void* __restrict__ Cv,
                                                 int M, int N, int K, int c_bf16) {
    __shared__ unsigned short As[128 * 64];
    __shared__ unsigned short Bs[64 * 64];
    const int tid = threadIdx.x;
    const int wave = tid >> 6, lane = tid & 63;
    const int m16 = lane & 15, quad = lane >> 4;
    const int m0 = blockIdx.y * 128, n0 = blockIdx.x * 64;
    const int wm = (wave >> 1) * 64, wn = (wave & 1) * 32;

    const int lrow = lane >> 3;
    const int gc = (lane & 7) ^ lrow;
    const unsigned short* Ab = A + (size_t)(m0 + wave * 8 + lrow) * K + gc * 8;
    const unsigned short* Bb = Bt + (size_t)(n0 + wave * 8 + lrow) * K + gc * 8;

    f32x4 acc[4][2];
#pragma unroll
    for (int mb = 0; mb < 4; mb++)
#pragma unroll
        for (int nb = 0; nb < 2; nb++) acc[mb][nb] = (f32x4){0.f, 0.f, 0.f, 0.f};

    for (int k0 = 0; k0 < K; k0 += 64) {
#pragma unroll
        for (int g = 0; g < 4; g++)
            gl_lds16(Ab + (size_t)g * 32 * K + k0, &As[(g * 32 + wave * 8) * 64]);
#pragma unroll
        for (int g = 0; g < 2; g++)
            gl_lds16(Bb + (size_t)g * 32 * K + k0, &Bs[(g * 32 + wave * 8) * 64]);
        __syncthreads();
#pragma unroll
        for (int ks = 0; ks < 2; ks++) {
            const int ch = (ks * 4 + quad) ^ (m16 & 7);
            bf16x8 af[4], bfr[2];
#pragma unroll
            for (int mb = 0; mb < 4; mb++)
                af[mb] = *(const bf16x8*)&As[(wm + mb * 16 + m16) * 64 + ch * 8];
#pragma unroll
            for (int nb = 0; nb < 2; nb++)
                bfr[nb] = *(const bf16x8*)&Bs[(wn + nb * 16 + m16) * 64 + ch * 8];
#pragma unroll
            for (int mb = 0; mb < 4; mb++)
#pragma unroll
                for (int nb = 0; nb < 2; nb++)
                    acc[mb][nb] = __builtin_amdgcn_mfma_f32_16x16x32_bf16(af[mb], bfr[nb], acc[mb][nb], 0, 0, 0);
        }
        __syncthreads();
    }

    if (c_bf16) {
        unsigned short* C = (unsigned short*)Cv;
#pragma unroll
        for (int mb = 0; mb < 4; mb++)
#pragma unroll
            for (int nb = 0; nb < 2; nb++)
#pragma unroll
                for (int r = 0; r < 4; r++)
                    C[(size_t)(m0 + wm + mb * 16 + quad * 4 + r) * N + n0 + wn + nb * 16 + m16] =
                        bf16_of(acc[mb][nb][r]);
    } else {
        float* C = (float*)Cv;
#pragma unroll
        for (int mb = 0; mb < 4; mb++)
#pragma unroll
            for (int nb = 0; nb < 2; nb++)
#pragma unroll
                for (int r = 0; r < 4; r++)
                    C[(size_t)(m0 + wm + mb * 16 + quad * 4 + r) * N + n0 + wn + nb * 16 + m16] =
                        acc[mb][nb][r];
    }
}

// ---------------------------------------------------------------------------
// rope_tv: fused RoPE (blocks 0..2559) + V transpose-with-key-permute
// (blocks 2560..2815).  Q pre-scaled by 0.125*log2(e) (exp2 domain).
// V perm within each 128-key block matches the attention PV A-frag order.
// ---------------------------------------------------------------------------
__global__ __launch_bounds__(256) void rope_tv(const unsigned short* __restrict__ qkv,
                                               unsigned short* __restrict__ qbf,
                                               unsigned short* __restrict__ kbf,
                                               unsigned short* __restrict__ vbt,
                                               const float* __restrict__ fcos,
                                               const float* __restrict__ fsin) {
    __shared__ unsigned short tile[64][65];
    const int t = threadIdx.x;
    int b = blockIdx.x;
    if (b < 2560) {
        int idx = b * 256 + t;
        const int nq = S_LEN * N_HEADS * 8;
        int s, j, srcoff, dstoff;
        unsigned short* dst;
        float osc;
        if (idx < nq) {
            s = idx >> 8;
            int rem = idx & 255;
            int h = rem >> 3;
            j = rem & 7;
            srcoff = s * QKV_N + h * 64 + j * 8;
            dstoff = s * DIM + h * 64 + j * 8;
            dst = qbf;
            osc = QSCALE;
        } else {
            int t2 = idx - nq;
            s = t2 >> 6;
            int rem = t2 & 63;
            int h = rem >> 3;
            j = rem & 7;
            srcoff = s * QKV_N + DIM + h * 64 + j * 8;
            dstoff = s * KV_DIM + h * 64 + j * 8;
            dst = kbf;
            osc = 1.0f;
        }
        bf16x8 v8 = *(const bf16x8*)&qkv[srcoff];
        float4 c4 = *(const float4*)&fcos[s * 32 + j * 4];
        float4 s4 = *(const float4*)&fsin[s * 32 + j * 4];
        float cs[4] = {c4.x, c4.y, c4.z, c4.w};
        float sn[4] = {s4.x, s4.y, s4.z, s4.w};
        bf16x8 o;
#pragma unroll
        for (int p = 0; p < 4; p++) {
            float a = f_of_bf16((unsigned short)v8[2 * p]);
            float bb = f_of_bf16((unsigned short)v8[2 * p + 1]);
            o[2 * p]     = (short)bf16_of((a * cs[p] - bb * sn[p]) * osc);
            o[2 * p + 1] = (short)bf16_of((a * sn[p] + bb * cs[p]) * osc);
        }
        *(bf16x8*)&dst[dstoff] = o;
        return;
    }
    b -= 2560;                                    // 0..255  (8 x 32)
    const int d0 = (b & 7) * 64;
    const int s0 = (b >> 3) * 64;
#pragma unroll
    for (int i = 0; i < 16; i++) {
        int idx = t + i * 256;
        int r = idx >> 6, c = idx & 63;
        tile[r][c] = qkv[(size_t)(s0 + r) * QKV_N + DIM + KV_DIM + d0 + c];
    }
    __syncthreads();
#pragma unroll
    for (int i = 0; i < 16; i++) {
        int idx = t + i * 256;
        int r = idx >> 6, c = idx & 63;
        int key = s0 + c;
        int kl = key & 127;
        int kp = (kl & 0x60) | ((kl & 0x0C) << 1) | ((kl & 0x10) >> 2) | (kl & 3);
        vbt[(size_t)(d0 + r) * S_LEN + (key & ~127) + kp] = tile[c][r];
    }
}

// ---------------------------------------------------------------------------
// Flash attention v5: no split-K (R5 showed occupancy is not the limiter).
// Block = (head, paired q-tiles qt=31-bx then qt=bx) -> uniform 17 iters.
// Per-iteration cost cuts:
//   - double-buffered K/V DMA staging: ONE barrier/iter, DMA overlaps compute
//   - l via MFMA ones-trick: row-sum of P is a 5th accumulator column
//     (replaces 32 adds + 2 shuffles/iter; epilogue needs no shuffles)
//   - P packed with v_perm_b32 truncation (1 instr per bf16 pair)
// S^T operand-swap trick + in-register P + exp2-domain softmax as before.
// ---------------------------------------------------------------------------
__global__ __launch_bounds__(256) void attn_mfma5(const unsigned short* __restrict__ qb,
                                                  const unsigned short* __restrict__ kb,
                                                  const unsigned short* __restrict__ vbt,
                                                  unsigned short* __restrict__ out) {
    const int h  = blockIdx.y;
    const int bx = blockIdx.x;                    // 0..15
    const int kh = h >> 2;
    const int tid  = threadIdx.x;
    const int wave = tid >> 6;
    const int lane = tid & 63;
    const int m16  = lane & 15;
    const int quad = lane >> 4;

    __shared__ unsigned short Ks[2][128 * 64];    // [key][dim], chunk-swizzled
    __shared__ unsigned short Vt[2][64 * 128];    // [dim][key(perm)], chunk-swizzled

    const int lrow8 = lane >> 3;
    const int kc    = (lane & 7) ^ lrow8;
    const int lrow4 = lane >> 4;
    const int vc    = (lane & 15) ^ ((wave * 4 + lrow4) & 7);

    const unsigned short* Kbase = kb + (size_t)kh * 64 + (size_t)(wave * 8 + lrow8) * KV_DIM + kc * 8;
    const unsigned short* Vbase = vbt + (size_t)(kh * 64 + wave * 4 + lrow4) * S_LEN + vc * 8;

    bf16x8 ones;
#pragma unroll
    for (int i = 0; i < 8; i++) ones[i] = (short)0x3F80;   // 1.0 bf16

#pragma unroll
    for (int half = 0; half < 2; half++) {
        const int qt = half ? bx : (31 - bx);
        const int q0 = qt * 64;
        const int n_iter = (qt >> 1) + 1;

        bf16x8 qa[2];
        {
            const int qrow = q0 + wave * 16 + m16;
#pragma unroll
            for (int ks = 0; ks < 2; ks++)
                qa[ks] = *(const bf16x8*)&qb[(size_t)qrow * DIM + h * 64 + ks * 32 + quad * 8];
        }

        f32x4 o_acc[4];
#pragma unroll
        for (int nb = 0; nb < 4; nb++) o_acc[nb] = (f32x4){0.f, 0.f, 0.f, 0.f};
        f32x4 l_acc = (f32x4){0.f, 0.f, 0.f, 0.f};
        float m_s = -1e30f;
        const int qrow_lane = q0 + wave * 16 + m16;
        const int orow_base = q0 + wave * 16 + quad * 4;

        if (half) __syncthreads();   // all waves done reading previous half's buffers

        // prologue: stage tile 0 into buffer 0
#pragma unroll
        for (int g = 0; g < 4; g++) {
            gl_lds16(Kbase + (size_t)(g * 32) * KV_DIM, &Ks[0][(g * 32 + wave * 8) * 64]);
            gl_lds16(Vbase + (size_t)g * 16 * S_LEN, &Vt[0][(g * 16 + wave * 4) * 128]);
        }

        for (int kt = 0; kt < n_iter; kt++) {
            __syncthreads();                       // buf[kt&1] DMA drained; prev reads done
            if (kt + 1 < n_iter) {
                const int nb2 = (kt + 1) & 1;
#pragma unroll
                for (int g = 0; g < 4; g++) {
                    gl_lds16(Kbase + (size_t)((kt + 1) * 128 + g * 32) * KV_DIM,
                             &Ks[nb2][(g * 32 + wave * 8) * 64]);
                    gl_lds16(Vbase + (size_t)g * 16 * S_LEN + (kt + 1) * 128,
                             &Vt[nb2][(g * 16 + wave * 4) * 128]);
                }
            }
            const unsigned short* K_ = Ks[kt & 1];
            const unsigned short* V_ = Vt[kt & 1];

            // ---- S^T = K Q^T : sc[cb] holds keys cb*16+quad*4+r, qrow m16 ----
            f32x4 sc[8];
#pragma unroll
            for (int cb = 0; cb < 8; cb++) sc[cb] = (f32x4){0.f, 0.f, 0.f, 0.f};
#pragma unroll
            for (int ks = 0; ks < 2; ks++) {
                const int slot = (ks * 4 + quad) ^ (m16 & 7);
#pragma unroll
                for (int cb = 0; cb < 8; cb++) {
                    bf16x8 kf = *(const bf16x8*)&K_[(cb * 16 + m16) * 64 + slot * 8];
                    sc[cb] = __builtin_amdgcn_mfma_f32_16x16x32_bf16(kf, qa[ks], sc[cb], 0, 0, 0);
                }
            }

            // ---- causal mask (last tile of this q-tile only) ----
            if (kt == n_iter - 1) {
#pragma unroll
                for (int cb = 0; cb < 8; cb++) {
                    int key = kt * 128 + cb * 16 + quad * 4;
#pragma unroll
                    for (int r = 0; r < 4; r++)
                        if (key + r > qrow_lane) sc[cb][r] = -1e30f;
                }
            }

            // ---- online softmax (exp2 domain; all 32 values are row m16) ----
            float rmax = fmaxf(fmaxf(sc[0][0], sc[0][1]), fmaxf(sc[0][2], sc[0][3]));
#pragma unroll
            for (int cb = 1; cb < 8; cb++) {
                float c1 = fmaxf(fmaxf(sc[cb][0], sc[cb][1]), fmaxf(sc[cb][2], sc[cb][3]));
                rmax = fmaxf(rmax, c1);
            }
            rmax = fmaxf(rmax, __shfl_xor(rmax, 16, 64));
            rmax = fmaxf(rmax, __shfl_xor(rmax, 32, 64));

            float mnew = fmaxf(m_s, rmax);
            float alpha = __builtin_amdgcn_exp2f(m_s - mnew);
            m_s = mnew;

#pragma unroll
            for (int cb = 0; cb < 8; cb++)
#pragma unroll
                for (int r = 0; r < 4; r++)
                    sc[cb][r] = __builtin_amdgcn_exp2f(sc[cb][r] - mnew);

            // ---- pack P fragments (truncation, 1 v_perm each) ----
            unsigned int P01[8], P23[8];
#pragma unroll
            for (int cb = 0; cb < 8; cb++) {
                P01[cb] = pack2tr(sc[cb][0], sc[cb][1]);
                P23[cb] = pack2tr(sc[cb][2], sc[cb][3]);
            }

            // ---- rescale O and l by alpha of row quad*4+r ----
#pragma unroll
            for (int r = 0; r < 4; r++) {
                float a_r = __shfl(alpha, quad * 4 + r, 64);
#pragma unroll
                for (int nb = 0; nb < 4; nb++) o_acc[nb][r] *= a_r;
                l_acc[r] *= a_r;
            }

            // ---- O += P V (and l += P @ ones) ----
#pragma unroll
            for (int ks = 0; ks < 4; ks++) {
                union { unsigned int u[4]; bf16x8 v; } pa;
                pa.u[0] = P01[2 * ks];     pa.u[1] = P23[2 * ks];
                pa.u[2] = P01[2 * ks + 1]; pa.u[3] = P23[2 * ks + 1];
                const int slot = (ks * 4 + quad) ^ (m16 & 7);
#pragma unroll
                for (int nb = 0; nb < 4; nb++) {
                    bf16x8 vf = *(const bf16x8*)&V_[(nb * 16 + m16) * 128 + slot * 8];
                    o_acc[nb] = __builtin_amdgcn_mfma_f32_16x16x32_bf16(pa.v, vf, o_acc[nb], 0, 0, 0);
                }
                l_acc = __builtin_amdgcn_mfma_f32_16x16x32_bf16(pa.v, ones, l_acc, 0, 0, 0);
            }
        }

        // ---- epilogue: normalize by l (already C-layout), store bf16 ----
#pragma unroll
        for (int r = 0; r < 4; r++) {
            float inv_l = 1.f / l_acc[r];
#pragma unroll
            for (int nb = 0; nb < 4; nb++)
                out[(size_t)(orow_base + r) * DIM + h * 64 + nb * 16 + m16] =
                    bf16_of(o_acc[nb][r] * inv_l);
        }
    }
}

// ---------------------------------------------------------------------------
extern "C" void kernel_launch(void* const* d_in, const int* in_sizes, int n_in,
                              void* d_out, int out_size, void* d_ws, size_t ws_size,
                              hipStream_t stream) {
    const float* x    = (const float*)d_in[0];
    const float* wq   = (const float*)d_in[1];
    const float* wk   = (const float*)d_in[2];
    const float* wv   = (const float*)d_in[3];
    const float* wo   = (const float*)d_in[4];
    const float* fcos = (const float*)d_in[5];
    const float* fsin = (const float*)d_in[6];

    char* ws = (char*)d_ws;
    const size_t MB = 1024 * 1024;
    unsigned short* xbf    = (unsigned short*)(ws);             //  8 MB [2048][2048]
    unsigned short* wqkvT  = (unsigned short*)(ws + 8 * MB);    // 12 MB [3072][2048]
    unsigned short* woT    = (unsigned short*)(ws + 20 * MB);   //  8 MB [2048][2048]
    unsigned short* qkvbf  = (unsigned short*)(ws + 28 * MB);   // 12 MB [2048][3072]
    unsigned short* vbt    = (unsigned short*)(ws + 40 * MB);   //  2 MB [512][2048]
    // aliases (producer runs strictly after aliased buffer is dead):
    unsigned short* qbf    = (unsigned short*)(ws + 8 * MB);    //  8 MB (over wqkvT)
    unsigned short* kbf    = (unsigned short*)(ws + 16 * MB);   //  2 MB (over wqkvT tail)
    unsigned short* attnbf = (unsigned short*)(ws);             //  8 MB (over xbf)

    // 1. convert x + transpose weights (fused)
    prep<<<4096 + 2560, 256, 0, stream>>>(x, wq, wk, wv, wo, xbf, wqkvT, woT);

    // 2. fused QKV projection (bf16 out)
    gemm_bt64<<<dim3(QKV_N / 64, S_LEN / 128), 256, 0, stream>>>(xbf, wqkvT, qkvbf,
                                                                 S_LEN, QKV_N, DIM, 1);

    // 3. RoPE + V transpose (fused)
    rope_tv<<<2560 + 256, 256, 0, stream>>>(qkvbf, qbf, kbf, vbt, fcos, fsin);

    // 4. flash attention (double-buffered, l-via-MFMA)
    attn_mfma5<<<dim3(16, N_HEADS), 256, 0, stream>>>(qbf, kbf, vbt, attnbf);

    // 5. output projection (fp32 out)
    gemm_bt64<<<dim3(DIM / 64, S_LEN / 128), 256, 0, stream>>>(attnbf, woT, d_out,
                                                               S_LEN, DIM, DIM, 0);
}